// Round 4
// baseline (1221.750 us; speedup 1.0000x reference)
//
#include <hip/hip_runtime.h>

#define L_SEQ 1024
#define DMODEL 1024

typedef __attribute__((ext_vector_type(8))) short short8;
typedef __attribute__((ext_vector_type(4))) float floatx4;

__device__ inline float bf2f(short s) {
    union { unsigned int u; float f; } v;
    v.u = ((unsigned int)(unsigned short)s) << 16;
    return v.f;
}
__device__ inline short f2bf(float f) {
    union { float f; unsigned int u; } v; v.f = f;
    unsigned int r = v.u + 0x7fff + ((v.u >> 16) & 1);
    return (short)(r >> 16);
}
// convert 8 consecutive fp32 (16B-aligned) to a bf16x8 MFMA fragment
__device__ inline short8 cvt8(const float* f) {
    const float4* p = (const float4*)f;
    float4 a = p[0], b = p[1];
    short8 r;
    r[0] = f2bf(a.x); r[1] = f2bf(a.y); r[2] = f2bf(a.z); r[3] = f2bf(a.w);
    r[4] = f2bf(b.x); r[5] = f2bf(b.y); r[6] = f2bf(b.z); r[7] = f2bf(b.w);
    return r;
}

// ---------------- proj = secondary_structure @ ss_w^T : (B*L, 16) fp32 ----------------
__global__ __launch_bounds__(256) void proj_kernel(const float* __restrict__ ss,
                                                   const float* __restrict__ ssw,
                                                   float* __restrict__ proj) {
    int idx = blockIdx.x * 256 + threadIdx.x;   // B*L*16 = 65536
    int h = idx & 15;
    int bl = idx >> 4;
    float s = 0.f;
#pragma unroll
    for (int d = 0; d < 8; ++d)
        s += ss[bl * 8 + d] * ssw[h * 8 + d];
    proj[bl * 16 + h] = s;
}

// ---------------- QKV: out = x @ W^T ; Q scaled by 1/8 ; V stored transposed ----------------
__global__ __launch_bounds__(256) void qkv_gemm(const float* __restrict__ x,
                                                const float* __restrict__ Wq,
                                                const float* __restrict__ Wk,
                                                const float* __restrict__ Wv,
                                                short* __restrict__ Q,
                                                short* __restrict__ K,
                                                short* __restrict__ Vt) {
    int mode = blockIdx.z;   // 0=Q 1=K 2=V
    const float* W = (mode == 0) ? Wq : ((mode == 1) ? Wk : Wv);
    int m0 = blockIdx.x * 16;
    int n0 = blockIdx.y * 64 + (threadIdx.x >> 6) * 16;
    int lane = threadIdx.x & 63;
    int fr = lane & 15, quad = lane >> 4;
    const float* af = x + (m0 + fr) * DMODEL + quad * 8;
    const float* bf_ = W + (n0 + fr) * DMODEL + quad * 8;
    floatx4 acc = {0.f, 0.f, 0.f, 0.f};
#pragma unroll
    for (int k = 0; k < 32; ++k)
        acc = __builtin_amdgcn_mfma_f32_16x16x32_bf16(cvt8(af + k * 32), cvt8(bf_ + k * 32), acc, 0, 0, 0);
#pragma unroll
    for (int r = 0; r < 4; ++r) {
        int m = m0 + quad * 4 + r;          // token
        int n = n0 + fr;                    // output dim
        int b = m >> 10, i = m & 1023;
        int h = n >> 6, d = n & 63;
        if (mode == 0)
            Q[((b * 16 + h) * L_SEQ + i) * 64 + d] = f2bf(acc[r] * 0.125f);
        else if (mode == 1)
            K[((b * 16 + h) * L_SEQ + i) * 64 + d] = f2bf(acc[r]);
        else
            Vt[((b * 16 + h) * 64 + d) * L_SEQ + i] = f2bf(acc[r]);
    }
}

// ---------------- attention with fused physics bias ----------------
#define PSTRIDE 1032
__global__ __launch_bounds__(256) void attn_kernel(const short* __restrict__ Q,
                                                   const short* __restrict__ K,
                                                   const short* __restrict__ Vt,
                                                   const float* __restrict__ pf,
                                                   const int* __restrict__ ids,
                                                   const float* __restrict__ im,
                                                   const float* __restrict__ proj,
                                                   const float* __restrict__ db,
                                                   const float* __restrict__ ps,
                                                   const float* __restrict__ dd,
                                                   short* __restrict__ ctx) {
    __shared__ __align__(16) short P[16 * PSTRIDE];
    __shared__ float part_max[4][16];
    __shared__ float part_sum[4][16];
    __shared__ float proj_i[16 * 16];
    __shared__ float im_sym[625];
    __shared__ int ids_i[16];
    int bh = blockIdx.x;            // b*16+h
    int b = bh >> 4, h = bh & 15;
    int i0 = blockIdx.y * 16;
    int w = threadIdx.x >> 6;
    int lane = threadIdx.x & 63;
    int fr = lane & 15, quad = lane >> 4;

    float decay = fminf(fmaxf(dd[0], 0.1f), 5.0f);
    float psig = 1.f / (1.f + __expf(-ps[0]));
    float dbias = db[h];

    // stage: proj rows for this i-tile, symmetric inter matrix, ids for i-rows
    {
        int t = threadIdx.x;
        int row = t >> 4, hh = t & 15;
        proj_i[row * 16 + hh] = proj[((b << 10) + i0 + row) * 16 + hh];
        for (int e = t; e < 625; e += 256) {
            int r = e / 25, c = e - r * 25;
            im_sym[e] = 0.5f * (im[r * 25 + c] + im[c * 25 + r]);
        }
        if (t < 16) ids_i[t] = min(max(ids[(b << 10) + i0 + t], 0), 24);
    }
    __syncthreads();

    // Q fragments (K=64 -> 2 mfma steps)
    const short8* qp = (const short8*)(Q + (bh * L_SEQ + i0 + fr) * 64 + quad * 8);
    short8 a0 = qp[0], a1 = qp[4];

    floatx4 accs[16];
#pragma unroll
    for (int jt = 0; jt < 16; ++jt) {
        int j0 = jt * 64 + w * 16;
        int j = j0 + fr;
        const short8* kp = (const short8*)(K + (bh * L_SEQ + j0 + fr) * 64 + quad * 8);
        floatx4 acc = {0.f, 0.f, 0.f, 0.f};
        acc = __builtin_amdgcn_mfma_f32_16x16x32_bf16(a0, kp[0], acc, 0, 0, 0);
        acc = __builtin_amdgcn_mfma_f32_16x16x32_bf16(a1, kp[4], acc, 0, 0, 0);
        // inline physics bias for (i = i0+quad*4+r, j)
        int idj = min(max(ids[(b << 10) + j], 0), 24);
        const float4* pj4 = (const float4*)(proj + (((b << 10) + j) << 4));
        float4 p0 = pj4[0], p1 = pj4[1], p2 = pj4[2], p3 = pj4[3];
#pragma unroll
        for (int r = 0; r < 4; ++r) {
            int i = i0 + (quad << 2) + r;
            float dist = fminf(fmaxf(pf[(b << 20) + (i << 10) + j], 0.1f), 50.0f);
            float dp = -__expf(decay * __logf(dist)) * psig;
            float inter = im_sym[ids_i[(quad << 2) + r] * 25 + idj] / (1.0f + fabsf((float)(i - j)));
            const float* pi = proj_i + ((quad << 2) + r) * 16;
            float dot = pi[0] * p0.x + pi[1] * p0.y + pi[2] * p0.z + pi[3] * p0.w
                      + pi[4] * p1.x + pi[5] * p1.y + pi[6] * p1.z + pi[7] * p1.w
                      + pi[8] * p2.x + pi[9] * p2.y + pi[10] * p2.z + pi[11] * p2.w
                      + pi[12] * p3.x + pi[13] * p3.y + pi[14] * p3.z + pi[15] * p3.w;
            float st = 1.f / (1.f + __expf(-dot)) - 0.5f;
            acc[r] += dp + inter + st + dbias;
        }
        accs[jt] = acc;
    }
    // row max
    float pm[4];
#pragma unroll
    for (int r = 0; r < 4; ++r) {
        float m = -1e30f;
#pragma unroll
        for (int jt = 0; jt < 16; ++jt) m = fmaxf(m, accs[jt][r]);
#pragma unroll
        for (int mask = 8; mask >= 1; mask >>= 1) m = fmaxf(m, __shfl_xor(m, mask));
        pm[r] = m;
    }
    if (fr == 0) {
#pragma unroll
        for (int r = 0; r < 4; ++r) part_max[w][quad * 4 + r] = pm[r];
    }
    __syncthreads();
    float M[4], psum[4];
#pragma unroll
    for (int r = 0; r < 4; ++r) {
        int ii = quad * 4 + r;
        M[r] = fmaxf(fmaxf(part_max[0][ii], part_max[1][ii]),
                     fmaxf(part_max[2][ii], part_max[3][ii]));
        psum[r] = 0.f;
    }
#pragma unroll
    for (int jt = 0; jt < 16; ++jt) {
        int j0 = jt * 64 + w * 16;
#pragma unroll
        for (int r = 0; r < 4; ++r) {
            float e = __expf(accs[jt][r] - M[r]);
            psum[r] += e;
            P[(quad * 4 + r) * PSTRIDE + j0 + fr] = f2bf(e);
        }
    }
#pragma unroll
    for (int r = 0; r < 4; ++r) {
#pragma unroll
        for (int mask = 8; mask >= 1; mask >>= 1) psum[r] += __shfl_xor(psum[r], mask);
    }
    if (fr == 0) {
#pragma unroll
        for (int r = 0; r < 4; ++r) part_sum[w][quad * 4 + r] = psum[r];
    }
    __syncthreads();
    float SUM[4];
#pragma unroll
    for (int r = 0; r < 4; ++r) {
        int ii = quad * 4 + r;
        SUM[r] = part_sum[0][ii] + part_sum[1][ii] + part_sum[2][ii] + part_sum[3][ii];
    }
    // PV: wave w handles d-cols w*16..w*16+15, contraction over j=1024
    const short8* vp = (const short8*)(Vt + (bh * 64 + w * 16 + fr) * L_SEQ + quad * 8);
    floatx4 acc = {0.f, 0.f, 0.f, 0.f};
#pragma unroll
    for (int ks = 0; ks < 32; ++ks) {
        short8 a = *(const short8*)(P + fr * PSTRIDE + quad * 8 + ks * 32);
        acc = __builtin_amdgcn_mfma_f32_16x16x32_bf16(a, vp[ks * 4], acc, 0, 0, 0);
    }
#pragma unroll
    for (int r = 0; r < 4; ++r) {
        int ii = quad * 4 + r;
        ctx[(b * L_SEQ + i0 + ii) * DMODEL + h * 64 + w * 16 + fr] = f2bf(acc[r] / SUM[r]);
    }
}

// ---------------- out = ctx @ Wo^T + bo  (fp32 output) ----------------
__global__ __launch_bounds__(256) void out_gemm(const short* __restrict__ ctx,
                                                const float* __restrict__ Wo,
                                                const float* __restrict__ bo,
                                                float* __restrict__ out) {
    int m0 = blockIdx.x * 16;
    int n0 = blockIdx.y * 64 + (threadIdx.x >> 6) * 16;
    int lane = threadIdx.x & 63;
    int fr = lane & 15, quad = lane >> 4;
    const short8* ap = (const short8*)(ctx + (m0 + fr) * DMODEL + quad * 8);
    const float* bf_ = Wo + (n0 + fr) * DMODEL + quad * 8;
    floatx4 acc = {0.f, 0.f, 0.f, 0.f};
#pragma unroll
    for (int k = 0; k < 32; ++k)
        acc = __builtin_amdgcn_mfma_f32_16x16x32_bf16(ap[k * 4], cvt8(bf_ + k * 32), acc, 0, 0, 0);
#pragma unroll
    for (int r = 0; r < 4; ++r) {
        int m = m0 + quad * 4 + r;
        int n = n0 + fr;
        out[m * DMODEL + n] = acc[r] + bo[n];
    }
}

extern "C" void kernel_launch(void* const* d_in, const int* in_sizes, int n_in,
                              void* d_out, int out_size, void* d_ws, size_t ws_size,
                              hipStream_t stream) {
    const float* x   = (const float*)d_in[0];
    const float* pf  = (const float*)d_in[1];
    const int*   ids = (const int*)d_in[2];
    const float* ss  = (const float*)d_in[3];
    const float* Wq  = (const float*)d_in[4];
    const float* Wk  = (const float*)d_in[5];
    const float* Wv  = (const float*)d_in[6];
    const float* Wo  = (const float*)d_in[7];
    const float* bo  = (const float*)d_in[8];
    const float* db  = (const float*)d_in[9];
    const float* im  = (const float*)d_in[10];
    const float* ssw = (const float*)d_in[11];
    const float* ps  = (const float*)d_in[12];
    const float* dd  = (const float*)d_in[13];
    float* out = (float*)d_out;

    char* ws = (char*)d_ws;
    short* Q    = (short*)(ws);                       //  8 MB
    short* K    = (short*)(ws + (8u  << 20));         //  8 MB
    short* Vt   = (short*)(ws + (16u << 20));         //  8 MB
    short* ctx  = (short*)(ws + (24u << 20));         //  8 MB
    float* proj = (float*)(ws + (32u << 20));         // 256 KB

    hipLaunchKernelGGL(proj_kernel, dim3(256), dim3(256), 0, stream, ss, ssw, proj);
    hipLaunchKernelGGL(qkv_gemm, dim3(256, 16, 3), dim3(256), 0, stream,
                       x, Wq, Wk, Wv, Q, K, Vt);
    hipLaunchKernelGGL(attn_kernel, dim3(64, 64), dim3(256), 0, stream,
                       Q, K, Vt, pf, ids, im, proj, db, ps, dd, ctx);
    hipLaunchKernelGGL(out_gemm, dim3(256, 16), dim3(256), 0, stream, ctx, Wo, bo, out);
}

// Round 5
// 457.265 us; speedup vs baseline: 2.6719x; 2.6719x over previous
//
#include <hip/hip_runtime.h>

#define L_SEQ 1024
#define DMODEL 1024

typedef __attribute__((ext_vector_type(8))) short short8;
typedef __attribute__((ext_vector_type(4))) float floatx4;

__device__ inline float bf2f(short s) {
    union { unsigned int u; float f; } v;
    v.u = ((unsigned int)(unsigned short)s) << 16;
    return v.f;
}
__device__ inline short f2bf(float f) {
    union { float f; unsigned int u; } v; v.f = f;
    unsigned int r = v.u + 0x7fff + ((v.u >> 16) & 1);
    return (short)(r >> 16);
}
__device__ inline void gload_lds16(const short* g, short* l) {
    __builtin_amdgcn_global_load_lds(
        (const __attribute__((address_space(1))) void*)g,
        (__attribute__((address_space(3))) void*)l, 16, 0, 0);
}

// ---------------- fp32 -> bf16 bulk convert (8 elems/thread) ----------------
__global__ __launch_bounds__(256) void cvt_kernel(const float* __restrict__ src,
                                                  short* __restrict__ dst) {
    int idx = blockIdx.x * 256 + threadIdx.x;
    const float4* p = (const float4*)src + idx * 2;
    float4 a = p[0], b = p[1];
    short8 r;
    r[0] = f2bf(a.x); r[1] = f2bf(a.y); r[2] = f2bf(a.z); r[3] = f2bf(a.w);
    r[4] = f2bf(b.x); r[5] = f2bf(b.y); r[6] = f2bf(b.z); r[7] = f2bf(b.w);
    *(short8*)(dst + idx * 8) = r;
}

// ---------------- proj = secondary_structure @ ss_w^T : (B*L, 16) fp32 ----------------
__global__ __launch_bounds__(256) void proj_kernel(const float* __restrict__ ss,
                                                   const float* __restrict__ ssw,
                                                   float* __restrict__ proj) {
    int idx = blockIdx.x * 256 + threadIdx.x;   // B*L*16 = 65536
    int h = idx & 15;
    int bl = idx >> 4;
    float s = 0.f;
#pragma unroll
    for (int d = 0; d < 8; ++d)
        s += ss[bl * 8 + d] * ssw[h * 8 + d];
    proj[bl * 16 + h] = s;
}

// ---------------- m97-style 128x128 GEMM: C = A(4096x1024) . B(3072x1024)^T ----------------
// epilogue scatters into Q (scaled), K, Vt per n-range
__global__ __launch_bounds__(256) void gemm_qkv(const short* __restrict__ xb,
                                                const short* __restrict__ Wb,
                                                short* __restrict__ Q,
                                                short* __restrict__ K,
                                                short* __restrict__ Vt) {
    __shared__ __align__(16) short As[128 * 32];
    __shared__ __align__(16) short Bs[128 * 32];
    int t = threadIdx.x;
    int wave = t >> 6, lane = t & 63, fr = lane & 15, quad = lane >> 4;
    int wm = (wave & 1) * 64, wn = (wave >> 1) * 64;
    int m0 = blockIdx.x * 128, n0 = blockIdx.y * 128;
    const short* Ag = xb + (m0 + (t >> 2)) * DMODEL + (t & 3) * 8;
    const short* Bg = Wb + (n0 + (t >> 2)) * DMODEL + (t & 3) * 8;
    short* Asd = As + t * 8;
    short* Bsd = Bs + t * 8;
    floatx4 acc[4][4] = {};
    for (int k0 = 0; k0 < DMODEL; k0 += 32) {
        __syncthreads();
        gload_lds16(Ag + k0, Asd);
        gload_lds16(Ag + 64 * DMODEL + k0, Asd + 2048);
        gload_lds16(Bg + k0, Bsd);
        gload_lds16(Bg + 64 * DMODEL + k0, Bsd + 2048);
        __syncthreads();
        short8 a[4], b[4];
#pragma unroll
        for (int i = 0; i < 4; ++i) {
            a[i] = *(const short8*)(As + (wm + i * 16 + fr) * 32 + quad * 8);
            b[i] = *(const short8*)(Bs + (wn + i * 16 + fr) * 32 + quad * 8);
        }
#pragma unroll
        for (int i = 0; i < 4; ++i)
#pragma unroll
            for (int j = 0; j < 4; ++j)
                acc[i][j] = __builtin_amdgcn_mfma_f32_16x16x32_bf16(a[i], b[j], acc[i][j], 0, 0, 0);
    }
#pragma unroll
    for (int i = 0; i < 4; ++i)
#pragma unroll
        for (int j = 0; j < 4; ++j)
#pragma unroll
            for (int r = 0; r < 4; ++r) {
                int m = m0 + wm + i * 16 + quad * 4 + r;
                int n = n0 + wn + j * 16 + fr;
                int b_ = m >> 10, ii = m & 1023;
                int mode = n >> 10, nn = n & 1023;
                int h = nn >> 6, d = nn & 63;
                float v = acc[i][j][r];
                if (mode == 0)
                    Q[((b_ * 16 + h) * L_SEQ + ii) * 64 + d] = f2bf(v * 0.125f);
                else if (mode == 1)
                    K[((b_ * 16 + h) * L_SEQ + ii) * 64 + d] = f2bf(v);
                else
                    Vt[((b_ * 16 + h) * 64 + d) * L_SEQ + ii] = f2bf(v);
            }
}

// ---------------- m97-style 128x128 GEMM: out = ctx(4096x1024) . Wo(1024x1024)^T + bo ----------------
__global__ __launch_bounds__(256) void gemm_out(const short* __restrict__ ctx,
                                                const short* __restrict__ Wob,
                                                const float* __restrict__ bo,
                                                float* __restrict__ out) {
    __shared__ __align__(16) short As[128 * 32];
    __shared__ __align__(16) short Bs[128 * 32];
    int t = threadIdx.x;
    int wave = t >> 6, lane = t & 63, fr = lane & 15, quad = lane >> 4;
    int wm = (wave & 1) * 64, wn = (wave >> 1) * 64;
    int m0 = blockIdx.x * 128, n0 = blockIdx.y * 128;
    const short* Ag = ctx + (m0 + (t >> 2)) * DMODEL + (t & 3) * 8;
    const short* Bg = Wob + (n0 + (t >> 2)) * DMODEL + (t & 3) * 8;
    short* Asd = As + t * 8;
    short* Bsd = Bs + t * 8;
    floatx4 acc[4][4] = {};
    for (int k0 = 0; k0 < DMODEL; k0 += 32) {
        __syncthreads();
        gload_lds16(Ag + k0, Asd);
        gload_lds16(Ag + 64 * DMODEL + k0, Asd + 2048);
        gload_lds16(Bg + k0, Bsd);
        gload_lds16(Bg + 64 * DMODEL + k0, Bsd + 2048);
        __syncthreads();
        short8 a[4], b[4];
#pragma unroll
        for (int i = 0; i < 4; ++i) {
            a[i] = *(const short8*)(As + (wm + i * 16 + fr) * 32 + quad * 8);
            b[i] = *(const short8*)(Bs + (wn + i * 16 + fr) * 32 + quad * 8);
        }
#pragma unroll
        for (int i = 0; i < 4; ++i)
#pragma unroll
            for (int j = 0; j < 4; ++j)
                acc[i][j] = __builtin_amdgcn_mfma_f32_16x16x32_bf16(a[i], b[j], acc[i][j], 0, 0, 0);
    }
#pragma unroll
    for (int i = 0; i < 4; ++i)
#pragma unroll
        for (int j = 0; j < 4; ++j)
#pragma unroll
            for (int r = 0; r < 4; ++r) {
                int m = m0 + wm + i * 16 + quad * 4 + r;
                int n = n0 + wn + j * 16 + fr;
                out[m * DMODEL + n] = acc[i][j][r] + bo[n];
            }
}

// ---------------- attention with fused physics bias ----------------
#define PSTRIDE 1032
__global__ __launch_bounds__(256) void attn_kernel(const short* __restrict__ Q,
                                                   const short* __restrict__ K,
                                                   const short* __restrict__ Vt,
                                                   const float* __restrict__ pf,
                                                   const int* __restrict__ ids,
                                                   const float* __restrict__ im,
                                                   const float* __restrict__ proj,
                                                   const float* __restrict__ db,
                                                   const float* __restrict__ ps,
                                                   const float* __restrict__ dd,
                                                   short* __restrict__ ctx) {
    __shared__ __align__(16) short P[16 * PSTRIDE];
    __shared__ float part_max[4][16];
    __shared__ float part_sum[4][16];
    __shared__ float proj_i[16 * 16];
    __shared__ float im_sym[625];
    __shared__ int ids_i[16];
    int bh = blockIdx.x;            // b*16+h
    int b = bh >> 4, h = bh & 15;
    int i0 = blockIdx.y * 16;
    int w = threadIdx.x >> 6;
    int lane = threadIdx.x & 63;
    int fr = lane & 15, quad = lane >> 4;

    float decay = fminf(fmaxf(dd[0], 0.1f), 5.0f);
    float psig = 1.f / (1.f + __expf(-ps[0]));
    float dbias = db[h];

    {
        int t = threadIdx.x;
        int row = t >> 4, hh = t & 15;
        proj_i[row * 16 + hh] = proj[((b << 10) + i0 + row) * 16 + hh];
        for (int e = t; e < 625; e += 256) {
            int r = e / 25, c = e - r * 25;
            im_sym[e] = 0.5f * (im[r * 25 + c] + im[c * 25 + r]);
        }
        if (t < 16) ids_i[t] = min(max(ids[(b << 10) + i0 + t], 0), 24);
    }
    __syncthreads();

    const short8* qp = (const short8*)(Q + (bh * L_SEQ + i0 + fr) * 64 + quad * 8);
    short8 a0 = qp[0], a1 = qp[4];

    floatx4 accs[16];
#pragma unroll
    for (int jt = 0; jt < 16; ++jt) {
        int j0 = jt * 64 + w * 16;
        int j = j0 + fr;
        const short8* kp = (const short8*)(K + (bh * L_SEQ + j0 + fr) * 64 + quad * 8);
        floatx4 acc = {0.f, 0.f, 0.f, 0.f};
        acc = __builtin_amdgcn_mfma_f32_16x16x32_bf16(a0, kp[0], acc, 0, 0, 0);
        acc = __builtin_amdgcn_mfma_f32_16x16x32_bf16(a1, kp[4], acc, 0, 0, 0);
        int idj = min(max(ids[(b << 10) + j], 0), 24);
        const float4* pj4 = (const float4*)(proj + (((b << 10) + j) << 4));
        float4 p0 = pj4[0], p1 = pj4[1], p2 = pj4[2], p3 = pj4[3];
#pragma unroll
        for (int r = 0; r < 4; ++r) {
            int i = i0 + (quad << 2) + r;
            float dist = fminf(fmaxf(pf[(b << 20) + (i << 10) + j], 0.1f), 50.0f);
            float dp = -__expf(decay * __logf(dist)) * psig;
            float inter = im_sym[ids_i[(quad << 2) + r] * 25 + idj] / (1.0f + fabsf((float)(i - j)));
            const float* pi = proj_i + ((quad << 2) + r) * 16;
            float dot = pi[0] * p0.x + pi[1] * p0.y + pi[2] * p0.z + pi[3] * p0.w
                      + pi[4] * p1.x + pi[5] * p1.y + pi[6] * p1.z + pi[7] * p1.w
                      + pi[8] * p2.x + pi[9] * p2.y + pi[10] * p2.z + pi[11] * p2.w
                      + pi[12] * p3.x + pi[13] * p3.y + pi[14] * p3.z + pi[15] * p3.w;
            float st = 1.f / (1.f + __expf(-dot)) - 0.5f;
            acc[r] += dp + inter + st + dbias;
        }
        accs[jt] = acc;
    }
    float pm[4];
#pragma unroll
    for (int r = 0; r < 4; ++r) {
        float m = -1e30f;
#pragma unroll
        for (int jt = 0; jt < 16; ++jt) m = fmaxf(m, accs[jt][r]);
#pragma unroll
        for (int mask = 8; mask >= 1; mask >>= 1) m = fmaxf(m, __shfl_xor(m, mask));
        pm[r] = m;
    }
    if (fr == 0) {
#pragma unroll
        for (int r = 0; r < 4; ++r) part_max[w][quad * 4 + r] = pm[r];
    }
    __syncthreads();
    float M[4], psum[4];
#pragma unroll
    for (int r = 0; r < 4; ++r) {
        int ii = quad * 4 + r;
        M[r] = fmaxf(fmaxf(part_max[0][ii], part_max[1][ii]),
                     fmaxf(part_max[2][ii], part_max[3][ii]));
        psum[r] = 0.f;
    }
#pragma unroll
    for (int jt = 0; jt < 16; ++jt) {
        int j0 = jt * 64 + w * 16;
#pragma unroll
        for (int r = 0; r < 4; ++r) {
            float e = __expf(accs[jt][r] - M[r]);
            psum[r] += e;
            P[(quad * 4 + r) * PSTRIDE + j0 + fr] = f2bf(e);
        }
    }
#pragma unroll
    for (int r = 0; r < 4; ++r) {
#pragma unroll
        for (int mask = 8; mask >= 1; mask >>= 1) psum[r] += __shfl_xor(psum[r], mask);
    }
    if (fr == 0) {
#pragma unroll
        for (int r = 0; r < 4; ++r) part_sum[w][quad * 4 + r] = psum[r];
    }
    __syncthreads();
    float SUM[4];
#pragma unroll
    for (int r = 0; r < 4; ++r) {
        int ii = quad * 4 + r;
        SUM[r] = part_sum[0][ii] + part_sum[1][ii] + part_sum[2][ii] + part_sum[3][ii];
    }
    const short8* vp = (const short8*)(Vt + (bh * 64 + w * 16 + fr) * L_SEQ + quad * 8);
    floatx4 acc = {0.f, 0.f, 0.f, 0.f};
#pragma unroll
    for (int ks = 0; ks < 32; ++ks) {
        short8 a = *(const short8*)(P + fr * PSTRIDE + quad * 8 + ks * 32);
        acc = __builtin_amdgcn_mfma_f32_16x16x32_bf16(a, vp[ks * 4], acc, 0, 0, 0);
    }
#pragma unroll
    for (int r = 0; r < 4; ++r) {
        int ii = quad * 4 + r;
        ctx[(b * L_SEQ + i0 + ii) * DMODEL + h * 64 + w * 16 + fr] = f2bf(acc[r] / SUM[r]);
    }
}

extern "C" void kernel_launch(void* const* d_in, const int* in_sizes, int n_in,
                              void* d_out, int out_size, void* d_ws, size_t ws_size,
                              hipStream_t stream) {
    const float* x   = (const float*)d_in[0];
    const float* pf  = (const float*)d_in[1];
    const int*   ids = (const int*)d_in[2];
    const float* ss  = (const float*)d_in[3];
    const float* Wq  = (const float*)d_in[4];
    const float* Wk  = (const float*)d_in[5];
    const float* Wv  = (const float*)d_in[6];
    const float* Wo  = (const float*)d_in[7];
    const float* bo  = (const float*)d_in[8];
    const float* db  = (const float*)d_in[9];
    const float* im  = (const float*)d_in[10];
    const float* ssw = (const float*)d_in[11];
    const float* ps  = (const float*)d_in[12];
    const float* dd  = (const float*)d_in[13];
    float* out = (float*)d_out;

    char* ws = (char*)d_ws;
    short* xb   = (short*)(ws);                       // 8 MB (reused as ctx)
    short* ctx  = (short*)(ws);
    short* Q    = (short*)(ws + (8u  << 20));         // 8 MB
    short* K    = (short*)(ws + (16u << 20));         // 8 MB
    short* Vt   = (short*)(ws + (24u << 20));         // 8 MB
    short* Wb   = (short*)(ws + (32u << 20));         // 6 MB (reused as Wob)
    short* Wob  = (short*)(ws + (32u << 20));
    float* proj = (float*)(ws + (38u << 20));         // 256 KB

    hipLaunchKernelGGL(cvt_kernel, dim3(2048), dim3(256), 0, stream, x, xb);
    hipLaunchKernelGGL(cvt_kernel, dim3(512), dim3(256), 0, stream, Wq, Wb);
    hipLaunchKernelGGL(cvt_kernel, dim3(512), dim3(256), 0, stream, Wk, Wb + (1u << 20));
    hipLaunchKernelGGL(cvt_kernel, dim3(512), dim3(256), 0, stream, Wv, Wb + (2u << 20));
    hipLaunchKernelGGL(proj_kernel, dim3(256), dim3(256), 0, stream, ss, ssw, proj);
    hipLaunchKernelGGL(gemm_qkv, dim3(32, 24), dim3(256), 0, stream, xb, Wb, Q, K, Vt);
    hipLaunchKernelGGL(attn_kernel, dim3(64, 64), dim3(256), 0, stream,
                       Q, K, Vt, pf, ids, im, proj, db, ps, dd, ctx);
    hipLaunchKernelGGL(cvt_kernel, dim3(512), dim3(256), 0, stream, Wo, Wob);
    hipLaunchKernelGGL(gemm_out, dim3(32, 8), dim3(256), 0, stream, ctx, Wob, bo, out);
}

// Round 6
// 401.189 us; speedup vs baseline: 3.0453x; 1.1398x over previous
//
#include <hip/hip_runtime.h>

#define L_SEQ 1024
#define DMODEL 1024

typedef __attribute__((ext_vector_type(8))) short short8;
typedef __attribute__((ext_vector_type(4))) short shortx4;
typedef __attribute__((ext_vector_type(4))) float floatx4;

__device__ inline float bf2f(short s) {
    union { unsigned int u; float f; } v;
    v.u = ((unsigned int)(unsigned short)s) << 16;
    return v.f;
}
__device__ inline short f2bf(float f) {
    union { float f; unsigned int u; } v; v.f = f;
    unsigned int r = v.u + 0x7fff + ((v.u >> 16) & 1);
    return (short)(r >> 16);
}
__device__ inline void gload_lds16(const short* g, short* l) {
    __builtin_amdgcn_global_load_lds(
        (const __attribute__((address_space(1))) void*)g,
        (__attribute__((address_space(3))) void*)l, 16, 0, 0);
}

// ---------------- fp32 -> bf16 bulk convert (8 elems/thread) ----------------
__global__ __launch_bounds__(256) void cvt_kernel(const float* __restrict__ src,
                                                  short* __restrict__ dst) {
    int idx = blockIdx.x * 256 + threadIdx.x;
    const float4* p = (const float4*)src + idx * 2;
    float4 a = p[0], b = p[1];
    short8 r;
    r[0] = f2bf(a.x); r[1] = f2bf(a.y); r[2] = f2bf(a.z); r[3] = f2bf(a.w);
    r[4] = f2bf(b.x); r[5] = f2bf(b.y); r[6] = f2bf(b.z); r[7] = f2bf(b.w);
    *(short8*)(dst + idx * 8) = r;
}

// ---------------- proj = secondary_structure @ ss_w^T : (B*L, 16) fp32 ----------------
__global__ __launch_bounds__(256) void proj_kernel(const float* __restrict__ ss,
                                                   const float* __restrict__ ssw,
                                                   float* __restrict__ proj) {
    int idx = blockIdx.x * 256 + threadIdx.x;   // B*L*16 = 65536
    int h = idx & 15;
    int bl = idx >> 4;
    float s = 0.f;
#pragma unroll
    for (int d = 0; d < 8; ++d)
        s += ss[bl * 8 + d] * ssw[h * 8 + d];
    proj[bl * 16 + h] = s;
}

// ---------------- bias(b,i,j) = dist_pen + inter + struct  (bf16, head-independent) ----------------
__global__ __launch_bounds__(256) void bias_kernel(const float* __restrict__ pf,
                                                   const int* __restrict__ ids,
                                                   const float* __restrict__ im,
                                                   const float* __restrict__ proj,
                                                   const float* __restrict__ ps,
                                                   const float* __restrict__ dd,
                                                   short* __restrict__ bias) {
    int b = blockIdx.y;
    int i = blockIdx.x;
    float decay = fminf(fmaxf(dd[0], 0.1f), 5.0f);
    float psig = 1.f / (1.f + __expf(-ps[0]));
    __shared__ float pi[16];
    __shared__ float interrow[25];
    int id_i = min(max(ids[(b << 10) + i], 0), 24);
    if (threadIdx.x < 16) pi[threadIdx.x] = proj[(((b << 10) + i) << 4) + threadIdx.x];
    if (threadIdx.x < 25)
        interrow[threadIdx.x] = 0.5f * (im[id_i * 25 + threadIdx.x] + im[threadIdx.x * 25 + id_i]);
    __syncthreads();
    int j0 = threadIdx.x * 4;
    float4 d4 = *(const float4*)(pf + ((b << 20) + (i << 10) + j0));
    float dv[4] = {d4.x, d4.y, d4.z, d4.w};
    shortx4 o;
#pragma unroll
    for (int e = 0; e < 4; ++e) {
        int j = j0 + e;
        float dist = fminf(fmaxf(dv[e], 0.1f), 50.0f);
        float dp = -__expf(decay * __logf(dist)) * psig;
        int idj = min(max(ids[(b << 10) + j], 0), 24);
        float inter = interrow[idj] / (1.0f + fabsf((float)(i - j)));
        const float4* pj4 = (const float4*)(proj + (((b << 10) + j) << 4));
        float4 p0 = pj4[0], p1 = pj4[1], p2 = pj4[2], p3 = pj4[3];
        float dot = pi[0] * p0.x + pi[1] * p0.y + pi[2] * p0.z + pi[3] * p0.w
                  + pi[4] * p1.x + pi[5] * p1.y + pi[6] * p1.z + pi[7] * p1.w
                  + pi[8] * p2.x + pi[9] * p2.y + pi[10] * p2.z + pi[11] * p2.w
                  + pi[12] * p3.x + pi[13] * p3.y + pi[14] * p3.z + pi[15] * p3.w;
        float st = 1.f / (1.f + __expf(-dot)) - 0.5f;
        o[e] = f2bf(dp + inter + st);
    }
    *(shortx4*)(bias + (((b << 10) + i) << 10) + j0) = o;
}

// ---------------- m97-style 128x128 GEMM: C = A(4096x1024) . B(3072x1024)^T ----------------
__global__ __launch_bounds__(256) void gemm_qkv(const short* __restrict__ xb,
                                                const short* __restrict__ Wb,
                                                short* __restrict__ Q,
                                                short* __restrict__ K,
                                                short* __restrict__ Vt) {
    __shared__ __align__(16) short As[128 * 32];
    __shared__ __align__(16) short Bs[128 * 32];
    int t = threadIdx.x;
    int wave = t >> 6, lane = t & 63, fr = lane & 15, quad = lane >> 4;
    int wm = (wave & 1) * 64, wn = (wave >> 1) * 64;
    int m0 = blockIdx.x * 128, n0 = blockIdx.y * 128;
    const short* Ag = xb + (m0 + (t >> 2)) * DMODEL + (t & 3) * 8;
    const short* Bg = Wb + (n0 + (t >> 2)) * DMODEL + (t & 3) * 8;
    short* Asd = As + t * 8;
    short* Bsd = Bs + t * 8;
    floatx4 acc[4][4] = {};
    for (int k0 = 0; k0 < DMODEL; k0 += 32) {
        __syncthreads();
        gload_lds16(Ag + k0, Asd);
        gload_lds16(Ag + 64 * DMODEL + k0, Asd + 2048);
        gload_lds16(Bg + k0, Bsd);
        gload_lds16(Bg + 64 * DMODEL + k0, Bsd + 2048);
        __syncthreads();
        short8 a[4], b[4];
#pragma unroll
        for (int i = 0; i < 4; ++i) {
            a[i] = *(const short8*)(As + (wm + i * 16 + fr) * 32 + quad * 8);
            b[i] = *(const short8*)(Bs + (wn + i * 16 + fr) * 32 + quad * 8);
        }
#pragma unroll
        for (int i = 0; i < 4; ++i)
#pragma unroll
            for (int j = 0; j < 4; ++j)
                acc[i][j] = __builtin_amdgcn_mfma_f32_16x16x32_bf16(a[i], b[j], acc[i][j], 0, 0, 0);
    }
#pragma unroll
    for (int i = 0; i < 4; ++i)
#pragma unroll
        for (int j = 0; j < 4; ++j)
#pragma unroll
            for (int r = 0; r < 4; ++r) {
                int m = m0 + wm + i * 16 + quad * 4 + r;
                int n = n0 + wn + j * 16 + fr;
                int b_ = m >> 10, ii = m & 1023;
                int mode = n >> 10, nn = n & 1023;
                int h = nn >> 6, d = nn & 63;
                float v = acc[i][j][r];
                if (mode == 0)
                    Q[((b_ * 16 + h) * L_SEQ + ii) * 64 + d] = f2bf(v * 0.125f);
                else if (mode == 1)
                    K[((b_ * 16 + h) * L_SEQ + ii) * 64 + d] = f2bf(v);
                else
                    Vt[((b_ * 16 + h) * 64 + d) * L_SEQ + ii] = f2bf(v);
            }
}

// ---------------- m97-style 128x128 GEMM: out = ctx(4096x1024) . Wo(1024x1024)^T + bo ----------------
__global__ __launch_bounds__(256) void gemm_out(const short* __restrict__ ctx,
                                                const short* __restrict__ Wob,
                                                const float* __restrict__ bo,
                                                float* __restrict__ out) {
    __shared__ __align__(16) short As[128 * 32];
    __shared__ __align__(16) short Bs[128 * 32];
    int t = threadIdx.x;
    int wave = t >> 6, lane = t & 63, fr = lane & 15, quad = lane >> 4;
    int wm = (wave & 1) * 64, wn = (wave >> 1) * 64;
    int m0 = blockIdx.x * 128, n0 = blockIdx.y * 128;
    const short* Ag = ctx + (m0 + (t >> 2)) * DMODEL + (t & 3) * 8;
    const short* Bg = Wob + (n0 + (t >> 2)) * DMODEL + (t & 3) * 8;
    short* Asd = As + t * 8;
    short* Bsd = Bs + t * 8;
    floatx4 acc[4][4] = {};
    for (int k0 = 0; k0 < DMODEL; k0 += 32) {
        __syncthreads();
        gload_lds16(Ag + k0, Asd);
        gload_lds16(Ag + 64 * DMODEL + k0, Asd + 2048);
        gload_lds16(Bg + k0, Bsd);
        gload_lds16(Bg + 64 * DMODEL + k0, Bsd + 2048);
        __syncthreads();
        short8 a[4], b[4];
#pragma unroll
        for (int i = 0; i < 4; ++i) {
            a[i] = *(const short8*)(As + (wm + i * 16 + fr) * 32 + quad * 8);
            b[i] = *(const short8*)(Bs + (wn + i * 16 + fr) * 32 + quad * 8);
        }
#pragma unroll
        for (int i = 0; i < 4; ++i)
#pragma unroll
            for (int j = 0; j < 4; ++j)
                acc[i][j] = __builtin_amdgcn_mfma_f32_16x16x32_bf16(a[i], b[j], acc[i][j], 0, 0, 0);
    }
#pragma unroll
    for (int i = 0; i < 4; ++i)
#pragma unroll
        for (int j = 0; j < 4; ++j)
#pragma unroll
            for (int r = 0; r < 4; ++r) {
                int m = m0 + wm + i * 16 + quad * 4 + r;
                int n = n0 + wn + j * 16 + fr;
                out[m * DMODEL + n] = acc[i][j][r] + bo[n];
            }
}

// ---------------- attention: QK^T + precomputed bias, softmax, PV ----------------
#define PSTRIDE 1032
__global__ __launch_bounds__(256) void attn_kernel(const short* __restrict__ Q,
                                                   const short* __restrict__ K,
                                                   const short* __restrict__ Vt,
                                                   const short* __restrict__ bias,
                                                   short* __restrict__ ctx) {
    __shared__ __align__(16) short P[16 * PSTRIDE];
    __shared__ float part_max[4][16];
    __shared__ float part_sum[4][16];
    int bh = blockIdx.x;            // b*16+h
    int b = bh >> 4, h = bh & 15;
    int i0 = blockIdx.y * 16;
    int w = threadIdx.x >> 6;
    int lane = threadIdx.x & 63;
    int fr = lane & 15, quad = lane >> 4;

    // Q fragments (K=64 -> 2 mfma steps)
    const short8* qp = (const short8*)(Q + (bh * L_SEQ + i0 + fr) * 64 + quad * 8);
    short8 a0 = qp[0], a1 = qp[4];

    const short* brow = bias + ((b << 10) + i0) * L_SEQ;
    floatx4 accs[16];
#pragma unroll
    for (int jt = 0; jt < 16; ++jt) {
        int j0 = jt * 64 + w * 16;
        const short8* kp = (const short8*)(K + (bh * L_SEQ + j0 + fr) * 64 + quad * 8);
        floatx4 acc = {0.f, 0.f, 0.f, 0.f};
        acc = __builtin_amdgcn_mfma_f32_16x16x32_bf16(a0, kp[0], acc, 0, 0, 0);
        acc = __builtin_amdgcn_mfma_f32_16x16x32_bf16(a1, kp[4], acc, 0, 0, 0);
#pragma unroll
        for (int r = 0; r < 4; ++r)
            acc[r] += bf2f(brow[(quad * 4 + r) * L_SEQ + j0 + fr]);   // dist_bias dropped: softmax-invariant
        accs[jt] = acc;
    }
    float pm[4];
#pragma unroll
    for (int r = 0; r < 4; ++r) {
        float m = -1e30f;
#pragma unroll
        for (int jt = 0; jt < 16; ++jt) m = fmaxf(m, accs[jt][r]);
#pragma unroll
        for (int mask = 8; mask >= 1; mask >>= 1) m = fmaxf(m, __shfl_xor(m, mask));
        pm[r] = m;
    }
    if (fr == 0) {
#pragma unroll
        for (int r = 0; r < 4; ++r) part_max[w][quad * 4 + r] = pm[r];
    }
    __syncthreads();
    float M[4], psum[4];
#pragma unroll
    for (int r = 0; r < 4; ++r) {
        int ii = quad * 4 + r;
        M[r] = fmaxf(fmaxf(part_max[0][ii], part_max[1][ii]),
                     fmaxf(part_max[2][ii], part_max[3][ii]));
        psum[r] = 0.f;
    }
#pragma unroll
    for (int jt = 0; jt < 16; ++jt) {
        int j0 = jt * 64 + w * 16;
#pragma unroll
        for (int r = 0; r < 4; ++r) {
            float e = __expf(accs[jt][r] - M[r]);
            psum[r] += e;
            P[(quad * 4 + r) * PSTRIDE + j0 + fr] = f2bf(e);
        }
    }
#pragma unroll
    for (int r = 0; r < 4; ++r) {
#pragma unroll
        for (int mask = 8; mask >= 1; mask >>= 1) psum[r] += __shfl_xor(psum[r], mask);
    }
    if (fr == 0) {
#pragma unroll
        for (int r = 0; r < 4; ++r) part_sum[w][quad * 4 + r] = psum[r];
    }
    __syncthreads();
    float SUM[4];
#pragma unroll
    for (int r = 0; r < 4; ++r) {
        int ii = quad * 4 + r;
        SUM[r] = part_sum[0][ii] + part_sum[1][ii] + part_sum[2][ii] + part_sum[3][ii];
    }
    const short8* vp = (const short8*)(Vt + (bh * 64 + w * 16 + fr) * L_SEQ + quad * 8);
    floatx4 acc = {0.f, 0.f, 0.f, 0.f};
#pragma unroll
    for (int ks = 0; ks < 32; ++ks) {
        short8 a = *(const short8*)(P + fr * PSTRIDE + quad * 8 + ks * 32);
        acc = __builtin_amdgcn_mfma_f32_16x16x32_bf16(a, vp[ks * 4], acc, 0, 0, 0);
    }
#pragma unroll
    for (int r = 0; r < 4; ++r) {
        int ii = quad * 4 + r;
        ctx[(b * L_SEQ + i0 + ii) * DMODEL + h * 64 + w * 16 + fr] = f2bf(acc[r] / SUM[r]);
    }
}

extern "C" void kernel_launch(void* const* d_in, const int* in_sizes, int n_in,
                              void* d_out, int out_size, void* d_ws, size_t ws_size,
                              hipStream_t stream) {
    const float* x   = (const float*)d_in[0];
    const float* pf  = (const float*)d_in[1];
    const int*   ids = (const int*)d_in[2];
    const float* ss  = (const float*)d_in[3];
    const float* Wq  = (const float*)d_in[4];
    const float* Wk  = (const float*)d_in[5];
    const float* Wv  = (const float*)d_in[6];
    const float* Wo  = (const float*)d_in[7];
    const float* bo  = (const float*)d_in[8];
    const float* im  = (const float*)d_in[10];
    const float* ssw = (const float*)d_in[11];
    const float* ps  = (const float*)d_in[12];
    const float* dd  = (const float*)d_in[13];
    float* out = (float*)d_out;

    // ws plan (40 MB total), overlays are strictly stream-ordered:
    //  [0,8M):   xb (until gemm_qkv)  -> bias (bias_kernel..attn) -> Wob (cvt after attn)
    //  [8,16M):  Q   [16,24M): K   [24,32M): Vt
    //  [32,38M): Wb (until gemm_qkv) -> ctx [32,40M) (attn..gemm_out)
    //  [38,38.25M): proj (until bias_kernel)
    char* ws = (char*)d_ws;
    short* xb   = (short*)(ws);
    short* bias = (short*)(ws);
    short* Wob  = (short*)(ws);
    short* Q    = (short*)(ws + (8u  << 20));
    short* K    = (short*)(ws + (16u << 20));
    short* Vt   = (short*)(ws + (24u << 20));
    short* Wb   = (short*)(ws + (32u << 20));
    short* ctx  = (short*)(ws + (32u << 20));
    float* proj = (float*)(ws + (38u << 20));

    hipLaunchKernelGGL(cvt_kernel, dim3(2048), dim3(256), 0, stream, x, xb);
    hipLaunchKernelGGL(cvt_kernel, dim3(512), dim3(256), 0, stream, Wq, Wb);
    hipLaunchKernelGGL(cvt_kernel, dim3(512), dim3(256), 0, stream, Wk, Wb + (1u << 20));
    hipLaunchKernelGGL(cvt_kernel, dim3(512), dim3(256), 0, stream, Wv, Wb + (2u << 20));
    hipLaunchKernelGGL(proj_kernel, dim3(256), dim3(256), 0, stream, ss, ssw, proj);
    hipLaunchKernelGGL(gemm_qkv, dim3(32, 24), dim3(256), 0, stream, xb, Wb, Q, K, Vt);
    hipLaunchKernelGGL(bias_kernel, dim3(1024, 4), dim3(256), 0, stream,
                       pf, ids, im, proj, ps, dd, bias);
    hipLaunchKernelGGL(attn_kernel, dim3(64, 64), dim3(256), 0, stream,
                       Q, K, Vt, bias, ctx);
    hipLaunchKernelGGL(cvt_kernel, dim3(512), dim3(256), 0, stream, Wo, Wob);
    hipLaunchKernelGGL(gemm_out, dim3(32, 8), dim3(256), 0, stream, ctx, Wob, bo, out);
}

// Round 7
// 344.674 us; speedup vs baseline: 3.5447x; 1.1640x over previous
//
#include <hip/hip_runtime.h>

#define L_SEQ 1024
#define DMODEL 1024

typedef __attribute__((ext_vector_type(8))) short short8;
typedef __attribute__((ext_vector_type(4))) short shortx4;
typedef __attribute__((ext_vector_type(4))) float floatx4;

__device__ inline float bf2f(short s) {
    union { unsigned int u; float f; } v;
    v.u = ((unsigned int)(unsigned short)s) << 16;
    return v.f;
}
__device__ inline short f2bf(float f) {
    union { float f; unsigned int u; } v; v.f = f;
    unsigned int r = v.u + 0x7fff + ((v.u >> 16) & 1);
    return (short)(r >> 16);
}
__device__ inline void gload_lds16(const short* g, short* l) {
    __builtin_amdgcn_global_load_lds(
        (const __attribute__((address_space(1))) void*)g,
        (__attribute__((address_space(3))) void*)l, 16, 0, 0);
}

// ---------------- fp32 -> bf16 bulk convert (8 elems/thread) ----------------
__global__ __launch_bounds__(256) void cvt_kernel(const float* __restrict__ src,
                                                  short* __restrict__ dst) {
    int idx = blockIdx.x * 256 + threadIdx.x;
    const float4* p = (const float4*)src + idx * 2;
    float4 a = p[0], b = p[1];
    short8 r;
    r[0] = f2bf(a.x); r[1] = f2bf(a.y); r[2] = f2bf(a.z); r[3] = f2bf(a.w);
    r[4] = f2bf(b.x); r[5] = f2bf(b.y); r[6] = f2bf(b.z); r[7] = f2bf(b.w);
    *(short8*)(dst + idx * 8) = r;
}

// ---------------- proj = secondary_structure @ ss_w^T : (B*L, 16) fp32 ----------------
__global__ __launch_bounds__(256) void proj_kernel(const float* __restrict__ ss,
                                                   const float* __restrict__ ssw,
                                                   float* __restrict__ proj) {
    int idx = blockIdx.x * 256 + threadIdx.x;   // B*L*16 = 65536
    int h = idx & 15;
    int bl = idx >> 4;
    float s = 0.f;
#pragma unroll
    for (int d = 0; d < 8; ++d)
        s += ss[bl * 8 + d] * ssw[h * 8 + d];
    proj[bl * 16 + h] = s;
}

// ---------------- bias(b,i,j) = dist_pen + inter + struct  (bf16, head-independent) ----------------
__global__ __launch_bounds__(256) void bias_kernel(const float* __restrict__ pf,
                                                   const int* __restrict__ ids,
                                                   const float* __restrict__ im,
                                                   const float* __restrict__ proj,
                                                   const float* __restrict__ ps,
                                                   const float* __restrict__ dd,
                                                   short* __restrict__ bias) {
    int b = blockIdx.y;
    int i = blockIdx.x;
    float decay = fminf(fmaxf(dd[0], 0.1f), 5.0f);
    float psig = 1.f / (1.f + __expf(-ps[0]));
    __shared__ float pi[16];
    __shared__ float interrow[25];
    int id_i = min(max(ids[(b << 10) + i], 0), 24);
    if (threadIdx.x < 16) pi[threadIdx.x] = proj[(((b << 10) + i) << 4) + threadIdx.x];
    if (threadIdx.x < 25)
        interrow[threadIdx.x] = 0.5f * (im[id_i * 25 + threadIdx.x] + im[threadIdx.x * 25 + id_i]);
    __syncthreads();
    int j0 = threadIdx.x * 4;
    float4 d4 = *(const float4*)(pf + ((b << 20) + (i << 10) + j0));
    float dv[4] = {d4.x, d4.y, d4.z, d4.w};
    shortx4 o;
#pragma unroll
    for (int e = 0; e < 4; ++e) {
        int j = j0 + e;
        float dist = fminf(fmaxf(dv[e], 0.1f), 50.0f);
        float dp = -__expf(decay * __logf(dist)) * psig;
        int idj = min(max(ids[(b << 10) + j], 0), 24);
        float inter = interrow[idj] / (1.0f + fabsf((float)(i - j)));
        const float4* pj4 = (const float4*)(proj + (((b << 10) + j) << 4));
        float4 p0 = pj4[0], p1 = pj4[1], p2 = pj4[2], p3 = pj4[3];
        float dot = pi[0] * p0.x + pi[1] * p0.y + pi[2] * p0.z + pi[3] * p0.w
                  + pi[4] * p1.x + pi[5] * p1.y + pi[6] * p1.z + pi[7] * p1.w
                  + pi[8] * p2.x + pi[9] * p2.y + pi[10] * p2.z + pi[11] * p2.w
                  + pi[12] * p3.x + pi[13] * p3.y + pi[14] * p3.z + pi[15] * p3.w;
        float st = 1.f / (1.f + __expf(-dot)) - 0.5f;
        o[e] = f2bf(dp + inter + st);
    }
    *(shortx4*)(bias + (((b << 10) + i) << 10) + j0) = o;
}

// ---------------- m97-style 128x128 GEMM: C = A(4096x1024) . B(3072x1024)^T ----------------
__global__ __launch_bounds__(256) void gemm_qkv(const short* __restrict__ xb,
                                                const short* __restrict__ Wb,
                                                short* __restrict__ Q,
                                                short* __restrict__ K,
                                                short* __restrict__ Vt) {
    __shared__ __align__(16) short As[128 * 32];
    __shared__ __align__(16) short Bs[128 * 32];
    int t = threadIdx.x;
    int wave = t >> 6, lane = t & 63, fr = lane & 15, quad = lane >> 4;
    int wm = (wave & 1) * 64, wn = (wave >> 1) * 64;
    int m0 = blockIdx.x * 128, n0 = blockIdx.y * 128;
    const short* Ag = xb + (m0 + (t >> 2)) * DMODEL + (t & 3) * 8;
    const short* Bg = Wb + (n0 + (t >> 2)) * DMODEL + (t & 3) * 8;
    short* Asd = As + t * 8;
    short* Bsd = Bs + t * 8;
    floatx4 acc[4][4] = {};
    for (int k0 = 0; k0 < DMODEL; k0 += 32) {
        __syncthreads();
        gload_lds16(Ag + k0, Asd);
        gload_lds16(Ag + 64 * DMODEL + k0, Asd + 2048);
        gload_lds16(Bg + k0, Bsd);
        gload_lds16(Bg + 64 * DMODEL + k0, Bsd + 2048);
        __syncthreads();
        short8 a[4], b[4];
#pragma unroll
        for (int i = 0; i < 4; ++i) {
            a[i] = *(const short8*)(As + (wm + i * 16 + fr) * 32 + quad * 8);
            b[i] = *(const short8*)(Bs + (wn + i * 16 + fr) * 32 + quad * 8);
        }
#pragma unroll
        for (int i = 0; i < 4; ++i)
#pragma unroll
            for (int j = 0; j < 4; ++j)
                acc[i][j] = __builtin_amdgcn_mfma_f32_16x16x32_bf16(a[i], b[j], acc[i][j], 0, 0, 0);
    }
#pragma unroll
    for (int i = 0; i < 4; ++i)
#pragma unroll
        for (int j = 0; j < 4; ++j)
#pragma unroll
            for (int r = 0; r < 4; ++r) {
                int m = m0 + wm + i * 16 + quad * 4 + r;
                int n = n0 + wn + j * 16 + fr;
                int b_ = m >> 10, ii = m & 1023;
                int mode = n >> 10, nn = n & 1023;
                int h = nn >> 6, d = nn & 63;
                float v = acc[i][j][r];
                if (mode == 0)
                    Q[((b_ * 16 + h) * L_SEQ + ii) * 64 + d] = f2bf(v * 0.125f);
                else if (mode == 1)
                    K[((b_ * 16 + h) * L_SEQ + ii) * 64 + d] = f2bf(v);
                else
                    Vt[((b_ * 16 + h) * 64 + d) * L_SEQ + ii] = f2bf(v);
            }
}

// ---------------- m97-style 128x128 GEMM: out = ctx(4096x1024) . Wo(1024x1024)^T + bo ----------------
__global__ __launch_bounds__(256) void gemm_out(const short* __restrict__ ctx,
                                                const short* __restrict__ Wob,
                                                const float* __restrict__ bo,
                                                float* __restrict__ out) {
    __shared__ __align__(16) short As[128 * 32];
    __shared__ __align__(16) short Bs[128 * 32];
    int t = threadIdx.x;
    int wave = t >> 6, lane = t & 63, fr = lane & 15, quad = lane >> 4;
    int wm = (wave & 1) * 64, wn = (wave >> 1) * 64;
    int m0 = blockIdx.x * 128, n0 = blockIdx.y * 128;
    const short* Ag = ctx + (m0 + (t >> 2)) * DMODEL + (t & 3) * 8;
    const short* Bg = Wob + (n0 + (t >> 2)) * DMODEL + (t & 3) * 8;
    short* Asd = As + t * 8;
    short* Bsd = Bs + t * 8;
    floatx4 acc[4][4] = {};
    for (int k0 = 0; k0 < DMODEL; k0 += 32) {
        __syncthreads();
        gload_lds16(Ag + k0, Asd);
        gload_lds16(Ag + 64 * DMODEL + k0, Asd + 2048);
        gload_lds16(Bg + k0, Bsd);
        gload_lds16(Bg + 64 * DMODEL + k0, Bsd + 2048);
        __syncthreads();
        short8 a[4], b[4];
#pragma unroll
        for (int i = 0; i < 4; ++i) {
            a[i] = *(const short8*)(As + (wm + i * 16 + fr) * 32 + quad * 8);
            b[i] = *(const short8*)(Bs + (wn + i * 16 + fr) * 32 + quad * 8);
        }
#pragma unroll
        for (int i = 0; i < 4; ++i)
#pragma unroll
            for (int j = 0; j < 4; ++j)
                acc[i][j] = __builtin_amdgcn_mfma_f32_16x16x32_bf16(a[i], b[j], acc[i][j], 0, 0, 0);
    }
#pragma unroll
    for (int i = 0; i < 4; ++i)
#pragma unroll
        for (int j = 0; j < 4; ++j)
#pragma unroll
            for (int r = 0; r < 4; ++r) {
                int m = m0 + wm + i * 16 + quad * 4 + r;
                int n = n0 + wn + j * 16 + fr;
                out[m * DMODEL + n] = acc[i][j][r] + bo[n];
            }
}

// ---------------- flash-style attention: 128 Q-rows/block, online softmax ----------------
// LDS strides padded (72 / 136 shorts) -> 2-way max bank aliasing (free, m136).
#define KSTR 72
#define VSTR 136
#define PSTR 136
__global__ __launch_bounds__(256, 2) void attn_kernel(const short* __restrict__ Q,
                                                      const short* __restrict__ K,
                                                      const short* __restrict__ Vt,
                                                      const short* __restrict__ bias,
                                                      short* __restrict__ ctx) {
    __shared__ __align__(16) short Ks[128 * KSTR];          // 18432 B
    __shared__ __align__(16) short Vs[64 * VSTR];           // 17408 B
    __shared__ __align__(16) short Ps[4 * 2 * 16 * PSTR];   // 34816 B
    int bh = blockIdx.x;            // b*16+h
    int b = bh >> 4, h = bh & 15;
    int i0 = blockIdx.y * 128;
    int t = threadIdx.x;
    int w = t >> 6, lane = t & 63, fr = lane & 15, quad = lane >> 4;
    const short* Kg = K + (bh << 16);
    const short* Vg = Vt + (bh << 16);
    const short* Bg = bias + (b << 20);
    short* myP = Ps + w * (2 * 16 * PSTR);

    // Q fragments for this wave's 32 rows (2 tiles of 16), K=64 -> 2 ksteps
    short8 qf[2][2];
#pragma unroll
    for (int it = 0; it < 2; ++it) {
        const short8* qp = (const short8*)(Q + ((bh << 10) + i0 + w * 32 + it * 16 + fr) * 64 + quad * 8);
        qf[it][0] = qp[0];
        qf[it][1] = qp[4];
    }
    float mrow[2][4], lrow[2][4];
    floatx4 pv[2][4] = {};
#pragma unroll
    for (int it = 0; it < 2; ++it)
#pragma unroll
        for (int r = 0; r < 4; ++r) { mrow[it][r] = -1e30f; lrow[it][r] = 0.f; }

    for (int jc = 0; jc < 8; ++jc) {
        __syncthreads();   // previous chunk's LDS reads done
        // stage K chunk: 128 rows (j) x 64 (d)
#pragma unroll
        for (int s = 0; s < 4; ++s) {
            int seg = s * 256 + t;
            short8 v = *(const short8*)(Kg + (jc * 128 + (seg >> 3)) * 64 + (seg & 7) * 8);
            *(short8*)(Ks + (seg >> 3) * KSTR + (seg & 7) * 8) = v;
        }
        // stage V chunk: 64 rows (d) x 128 (j)
#pragma unroll
        for (int s = 0; s < 4; ++s) {
            int seg = s * 256 + t;
            short8 v = *(const short8*)(Vg + (seg >> 4) * 1024 + jc * 128 + (seg & 15) * 8);
            *(short8*)(Vs + (seg >> 4) * VSTR + (seg & 15) * 8) = v;
        }
        __syncthreads();
        // QK^T for this chunk: sc[it][jt] = 16x16 tile
        floatx4 sc[2][8];
#pragma unroll
        for (int jt = 0; jt < 8; ++jt) {
            short8 kb0 = *(const short8*)(Ks + (jt * 16 + fr) * KSTR + quad * 8);
            short8 kb1 = *(const short8*)(Ks + (jt * 16 + fr) * KSTR + 32 + quad * 8);
#pragma unroll
            for (int it = 0; it < 2; ++it) {
                floatx4 a = {0.f, 0.f, 0.f, 0.f};
                a = __builtin_amdgcn_mfma_f32_16x16x32_bf16(qf[it][0], kb0, a, 0, 0, 0);
                a = __builtin_amdgcn_mfma_f32_16x16x32_bf16(qf[it][1], kb1, a, 0, 0, 0);
                sc[it][jt] = a;
            }
        }
        // add precomputed physics bias (dist_bias dropped: softmax-invariant)
#pragma unroll
        for (int it = 0; it < 2; ++it)
#pragma unroll
            for (int jt = 0; jt < 8; ++jt)
#pragma unroll
                for (int r = 0; r < 4; ++r)
                    sc[it][jt][r] += bf2f(Bg[(i0 + w * 32 + it * 16 + quad * 4 + r) * 1024
                                             + jc * 128 + jt * 16 + fr]);
        // online softmax update + P write (A-operand layout)
#pragma unroll
        for (int it = 0; it < 2; ++it) {
#pragma unroll
            for (int r = 0; r < 4; ++r) {
                float cm = sc[it][0][r];
#pragma unroll
                for (int jt = 1; jt < 8; ++jt) cm = fmaxf(cm, sc[it][jt][r]);
#pragma unroll
                for (int mask = 8; mask >= 1; mask >>= 1) cm = fmaxf(cm, __shfl_xor(cm, mask));
                float mnew = fmaxf(mrow[it][r], cm);
                float alpha = __expf(mrow[it][r] - mnew);
                mrow[it][r] = mnew;
                float s = 0.f;
#pragma unroll
                for (int jt = 0; jt < 8; ++jt) {
                    float e = __expf(sc[it][jt][r] - mnew);
                    s += e;
                    myP[(it * 16 + quad * 4 + r) * PSTR + jt * 16 + fr] = f2bf(e);
                }
#pragma unroll
                for (int mask = 8; mask >= 1; mask >>= 1) s += __shfl_xor(s, mask);
                lrow[it][r] = lrow[it][r] * alpha + s;
#pragma unroll
                for (int dt = 0; dt < 4; ++dt) pv[it][dt][r] *= alpha;
            }
        }
        // PV: per-wave P region, same-wave LDS in-order; contraction over 128 j (4 ksteps)
#pragma unroll
        for (int ks = 0; ks < 4; ++ks) {
            short8 pa[2], vb[4];
#pragma unroll
            for (int it = 0; it < 2; ++it)
                pa[it] = *(const short8*)(myP + (it * 16 + fr) * PSTR + ks * 32 + quad * 8);
#pragma unroll
            for (int dt = 0; dt < 4; ++dt)
                vb[dt] = *(const short8*)(Vs + (dt * 16 + fr) * VSTR + ks * 32 + quad * 8);
#pragma unroll
            for (int it = 0; it < 2; ++it)
#pragma unroll
                for (int dt = 0; dt < 4; ++dt)
                    pv[it][dt] = __builtin_amdgcn_mfma_f32_16x16x32_bf16(pa[it], vb[dt], pv[it][dt], 0, 0, 0);
        }
    }
    // epilogue: normalize and store ctx
#pragma unroll
    for (int it = 0; it < 2; ++it)
#pragma unroll
        for (int dt = 0; dt < 4; ++dt)
#pragma unroll
            for (int r = 0; r < 4; ++r) {
                int i = i0 + w * 32 + it * 16 + quad * 4 + r;
                ctx[((b << 10) + i) * DMODEL + h * 64 + dt * 16 + fr] = f2bf(pv[it][dt][r] / lrow[it][r]);
            }
}

extern "C" void kernel_launch(void* const* d_in, const int* in_sizes, int n_in,
                              void* d_out, int out_size, void* d_ws, size_t ws_size,
                              hipStream_t stream) {
    const float* x   = (const float*)d_in[0];
    const float* pf  = (const float*)d_in[1];
    const int*   ids = (const int*)d_in[2];
    const float* ss  = (const float*)d_in[3];
    const float* Wq  = (const float*)d_in[4];
    const float* Wk  = (const float*)d_in[5];
    const float* Wv  = (const float*)d_in[6];
    const float* Wo  = (const float*)d_in[7];
    const float* bo  = (const float*)d_in[8];
    const float* im  = (const float*)d_in[10];
    const float* ssw = (const float*)d_in[11];
    const float* ps  = (const float*)d_in[12];
    const float* dd  = (const float*)d_in[13];
    float* out = (float*)d_out;

    // ws plan (40 MB total), overlays are strictly stream-ordered:
    //  [0,8M):   xb (until gemm_qkv)  -> bias (bias_kernel..attn) -> Wob (cvt after attn)
    //  [8,16M):  Q   [16,24M): K   [24,32M): Vt
    //  [32,38M): Wb (until gemm_qkv) -> ctx [32,40M) (attn..gemm_out)
    //  [38,38.25M): proj (until bias_kernel)
    char* ws = (char*)d_ws;
    short* xb   = (short*)(ws);
    short* bias = (short*)(ws);
    short* Wob  = (short*)(ws);
    short* Q    = (short*)(ws + (8u  << 20));
    short* K    = (short*)(ws + (16u << 20));
    short* Vt   = (short*)(ws + (24u << 20));
    short* Wb   = (short*)(ws + (32u << 20));
    short* ctx  = (short*)(ws + (32u << 20));
    float* proj = (float*)(ws + (38u << 20));

    hipLaunchKernelGGL(cvt_kernel, dim3(2048), dim3(256), 0, stream, x, xb);
    hipLaunchKernelGGL(cvt_kernel, dim3(512), dim3(256), 0, stream, Wq, Wb);
    hipLaunchKernelGGL(cvt_kernel, dim3(512), dim3(256), 0, stream, Wk, Wb + (1u << 20));
    hipLaunchKernelGGL(cvt_kernel, dim3(512), dim3(256), 0, stream, Wv, Wb + (2u << 20));
    hipLaunchKernelGGL(proj_kernel, dim3(256), dim3(256), 0, stream, ss, ssw, proj);
    hipLaunchKernelGGL(gemm_qkv, dim3(32, 24), dim3(256), 0, stream, xb, Wb, Q, K, Vt);
    hipLaunchKernelGGL(bias_kernel, dim3(1024, 4), dim3(256), 0, stream,
                       pf, ids, im, proj, ps, dd, bias);
    hipLaunchKernelGGL(attn_kernel, dim3(64, 8), dim3(256), 0, stream,
                       Q, K, Vt, bias, ctx);
    hipLaunchKernelGGL(cvt_kernel, dim3(512), dim3(256), 0, stream, Wo, Wob);
    hipLaunchKernelGGL(gemm_out, dim3(32, 8), dim3(256), 0, stream, ctx, Wob, bo, out);
}

// Round 8
// 259.837 us; speedup vs baseline: 4.7020x; 1.3265x over previous
//
#include <hip/hip_runtime.h>

#define L_SEQ 1024
#define DMODEL 1024

typedef __attribute__((ext_vector_type(8))) short short8;
typedef __attribute__((ext_vector_type(4))) short shortx4;
typedef __attribute__((ext_vector_type(4))) float floatx4;

__device__ inline float bf2f(short s) {
    union { unsigned int u; float f; } v;
    v.u = ((unsigned int)(unsigned short)s) << 16;
    return v.f;
}
__device__ inline short f2bf(float f) {
    union { float f; unsigned int u; } v; v.f = f;
    unsigned int r = v.u + 0x7fff + ((v.u >> 16) & 1);
    return (short)(r >> 16);
}
__device__ inline void gload_lds16(const short* g, short* l) {
    __builtin_amdgcn_global_load_lds(
        (const __attribute__((address_space(1))) void*)g,
        (__attribute__((address_space(3))) void*)l, 16, 0, 0);
}

// ---------------- fp32 -> bf16 bulk convert (8 elems/thread) ----------------
__global__ __launch_bounds__(256) void cvt_kernel(const float* __restrict__ src,
                                                  short* __restrict__ dst) {
    int idx = blockIdx.x * 256 + threadIdx.x;
    const float4* p = (const float4*)src + idx * 2;
    float4 a = p[0], b = p[1];
    short8 r;
    r[0] = f2bf(a.x); r[1] = f2bf(a.y); r[2] = f2bf(a.z); r[3] = f2bf(a.w);
    r[4] = f2bf(b.x); r[5] = f2bf(b.y); r[6] = f2bf(b.z); r[7] = f2bf(b.w);
    *(short8*)(dst + idx * 8) = r;
}

// ---------------- proj = secondary_structure @ ss_w^T : (B*L, 16) fp32 ----------------
__global__ __launch_bounds__(256) void proj_kernel(const float* __restrict__ ss,
                                                   const float* __restrict__ ssw,
                                                   float* __restrict__ proj) {
    int idx = blockIdx.x * 256 + threadIdx.x;   // B*L*16 = 65536
    int h = idx & 15;
    int bl = idx >> 4;
    float s = 0.f;
#pragma unroll
    for (int d = 0; d < 8; ++d)
        s += ss[bl * 8 + d] * ssw[h * 8 + d];
    proj[bl * 16 + h] = s;
}

// ---------------- bias in MFMA-C tile order: [b][ti][tj][(quad*16+fr)*4 + r] ----------------
__global__ __launch_bounds__(256) void bias_kernel(const float* __restrict__ pf,
                                                   const int* __restrict__ ids,
                                                   const float* __restrict__ im,
                                                   const float* __restrict__ proj,
                                                   const float* __restrict__ ps,
                                                   const float* __restrict__ dd,
                                                   short* __restrict__ biasT) {
    int b = blockIdx.y;
    int i = blockIdx.x;
    float decay = fminf(fmaxf(dd[0], 0.1f), 5.0f);
    float psig = 1.f / (1.f + __expf(-ps[0]));
    __shared__ float pi[16];
    __shared__ float interrow[25];
    int id_i = min(max(ids[(b << 10) + i], 0), 24);
    if (threadIdx.x < 16) pi[threadIdx.x] = proj[(((b << 10) + i) << 4) + threadIdx.x];
    if (threadIdx.x < 25)
        interrow[threadIdx.x] = 0.5f * (im[id_i * 25 + threadIdx.x] + im[threadIdx.x * 25 + id_i]);
    __syncthreads();
    int ti = i >> 4, iq = (i >> 2) & 3, ir = i & 3;
    int j0 = threadIdx.x * 4;
    float4 d4 = *(const float4*)(pf + ((b << 20) + (i << 10) + j0));
    float dv[4] = {d4.x, d4.y, d4.z, d4.w};
#pragma unroll
    for (int e = 0; e < 4; ++e) {
        int j = j0 + e;
        float dist = fminf(fmaxf(dv[e], 0.1f), 50.0f);
        float dp = -__expf(decay * __logf(dist)) * psig;
        int idj = min(max(ids[(b << 10) + j], 0), 24);
        float inter = interrow[idj] / (1.0f + fabsf((float)(i - j)));
        const float4* pj4 = (const float4*)(proj + (((b << 10) + j) << 4));
        float4 p0 = pj4[0], p1 = pj4[1], p2 = pj4[2], p3 = pj4[3];
        float dot = pi[0] * p0.x + pi[1] * p0.y + pi[2] * p0.z + pi[3] * p0.w
                  + pi[4] * p1.x + pi[5] * p1.y + pi[6] * p1.z + pi[7] * p1.w
                  + pi[8] * p2.x + pi[9] * p2.y + pi[10] * p2.z + pi[11] * p2.w
                  + pi[12] * p3.x + pi[13] * p3.y + pi[14] * p3.z + pi[15] * p3.w;
        float st = 1.f / (1.f + __expf(-dot)) - 0.5f;
        int tj = j >> 4, jf = j & 15;
        biasT[((((b << 6) + ti) << 6) + tj) * 256 + (iq * 16 + jf) * 4 + ir] =
            f2bf(dp + inter + st);
    }
}

// ---------------- m97-style 128x128 GEMM: C = A(4096x1024) . B(3072x1024)^T ----------------
__global__ __launch_bounds__(256) void gemm_qkv(const short* __restrict__ xb,
                                                const short* __restrict__ Wb,
                                                short* __restrict__ Q,
                                                short* __restrict__ K,
                                                short* __restrict__ Vt) {
    __shared__ __align__(16) short As[128 * 32];
    __shared__ __align__(16) short Bs[128 * 32];
    int t = threadIdx.x;
    int wave = t >> 6, lane = t & 63, fr = lane & 15, quad = lane >> 4;
    int wm = (wave & 1) * 64, wn = (wave >> 1) * 64;
    int m0 = blockIdx.x * 128, n0 = blockIdx.y * 128;
    const short* Ag = xb + (m0 + (t >> 2)) * DMODEL + (t & 3) * 8;
    const short* Bg = Wb + (n0 + (t >> 2)) * DMODEL + (t & 3) * 8;
    short* Asd = As + t * 8;
    short* Bsd = Bs + t * 8;
    floatx4 acc[4][4] = {};
    for (int k0 = 0; k0 < DMODEL; k0 += 32) {
        __syncthreads();
        gload_lds16(Ag + k0, Asd);
        gload_lds16(Ag + 64 * DMODEL + k0, Asd + 2048);
        gload_lds16(Bg + k0, Bsd);
        gload_lds16(Bg + 64 * DMODEL + k0, Bsd + 2048);
        __syncthreads();
        short8 a[4], b[4];
#pragma unroll
        for (int i = 0; i < 4; ++i) {
            a[i] = *(const short8*)(As + (wm + i * 16 + fr) * 32 + quad * 8);
            b[i] = *(const short8*)(Bs + (wn + i * 16 + fr) * 32 + quad * 8);
        }
#pragma unroll
        for (int i = 0; i < 4; ++i)
#pragma unroll
            for (int j = 0; j < 4; ++j)
                acc[i][j] = __builtin_amdgcn_mfma_f32_16x16x32_bf16(a[i], b[j], acc[i][j], 0, 0, 0);
    }
#pragma unroll
    for (int i = 0; i < 4; ++i)
#pragma unroll
        for (int j = 0; j < 4; ++j)
#pragma unroll
            for (int r = 0; r < 4; ++r) {
                int m = m0 + wm + i * 16 + quad * 4 + r;
                int n = n0 + wn + j * 16 + fr;
                int b_ = m >> 10, ii = m & 1023;
                int mode = n >> 10, nn = n & 1023;
                int h = nn >> 6, d = nn & 63;
                float v = acc[i][j][r];
                if (mode == 0)
                    Q[((b_ * 16 + h) * L_SEQ + ii) * 64 + d] = f2bf(v * 0.125f);
                else if (mode == 1)
                    K[((b_ * 16 + h) * L_SEQ + ii) * 64 + d] = f2bf(v);
                else
                    Vt[((b_ * 16 + h) * 64 + d) * L_SEQ + ii] = f2bf(v);
            }
}

// ---------------- m97-style 128x128 GEMM: out = ctx(4096x1024) . Wo(1024x1024)^T + bo ----------------
__global__ __launch_bounds__(256) void gemm_out(const short* __restrict__ ctx,
                                                const short* __restrict__ Wob,
                                                const float* __restrict__ bo,
                                                float* __restrict__ out) {
    __shared__ __align__(16) short As[128 * 32];
    __shared__ __align__(16) short Bs[128 * 32];
    int t = threadIdx.x;
    int wave = t >> 6, lane = t & 63, fr = lane & 15, quad = lane >> 4;
    int wm = (wave & 1) * 64, wn = (wave >> 1) * 64;
    int m0 = blockIdx.x * 128, n0 = blockIdx.y * 128;
    const short* Ag = ctx + (m0 + (t >> 2)) * DMODEL + (t & 3) * 8;
    const short* Bg = Wob + (n0 + (t >> 2)) * DMODEL + (t & 3) * 8;
    short* Asd = As + t * 8;
    short* Bsd = Bs + t * 8;
    floatx4 acc[4][4] = {};
    for (int k0 = 0; k0 < DMODEL; k0 += 32) {
        __syncthreads();
        gload_lds16(Ag + k0, Asd);
        gload_lds16(Ag + 64 * DMODEL + k0, Asd + 2048);
        gload_lds16(Bg + k0, Bsd);
        gload_lds16(Bg + 64 * DMODEL + k0, Bsd + 2048);
        __syncthreads();
        short8 a[4], b[4];
#pragma unroll
        for (int i = 0; i < 4; ++i) {
            a[i] = *(const short8*)(As + (wm + i * 16 + fr) * 32 + quad * 8);
            b[i] = *(const short8*)(Bs + (wn + i * 16 + fr) * 32 + quad * 8);
        }
#pragma unroll
        for (int i = 0; i < 4; ++i)
#pragma unroll
            for (int j = 0; j < 4; ++j)
                acc[i][j] = __builtin_amdgcn_mfma_f32_16x16x32_bf16(a[i], b[j], acc[i][j], 0, 0, 0);
    }
#pragma unroll
    for (int i = 0; i < 4; ++i)
#pragma unroll
        for (int j = 0; j < 4; ++j)
#pragma unroll
            for (int r = 0; r < 4; ++r) {
                int m = m0 + wm + i * 16 + quad * 4 + r;
                int n = n0 + wn + j * 16 + fr;
                out[m * DMODEL + n] = acc[i][j][r] + bo[n];
            }
}

// ---------------- flash attention, max-free softmax, double-buffered K/V ----------------
#define KSTR 72
#define VSTR 136
#define PSTR 136
__global__ __launch_bounds__(256, 2) void attn_kernel(const short* __restrict__ Q,
                                                      const short* __restrict__ K,
                                                      const short* __restrict__ Vt,
                                                      const short* __restrict__ biasT,
                                                      short* __restrict__ ctx) {
    __shared__ __align__(16) short Ks[128 * KSTR];          // 18432 B
    __shared__ __align__(16) short Vs[64 * VSTR];           // 17408 B
    __shared__ __align__(16) short Ps[4 * 2 * 16 * PSTR];   // 34816 B
    int bh = blockIdx.x;            // b*16+h
    int b = bh >> 4, h = bh & 15;
    int i0 = blockIdx.y * 128;
    int t = threadIdx.x;
    int w = t >> 6, lane = t & 63, fr = lane & 15, quad = lane >> 4;
    const short* Kg = K + (bh << 16);
    const short* Vg = Vt + (bh << 16);
    short* myP = Ps + w * (2 * 16 * PSTR);
    // bias tile-row bases (×64) for this wave's two i-tiles
    int tib[2];
    tib[0] = (((b << 6) + (i0 >> 4) + w * 2) << 6);
    tib[1] = tib[0] + 64;

    // Q fragments for this wave's 32 rows (2 tiles of 16)
    short8 qf[2][2];
#pragma unroll
    for (int it = 0; it < 2; ++it) {
        const short8* qp = (const short8*)(Q + ((bh << 10) + i0 + w * 32 + it * 16 + fr) * 64 + quad * 8);
        qf[it][0] = qp[0];
        qf[it][1] = qp[4];
    }
    float psum[2][4] = {};
    floatx4 pv[2][4] = {};

    // prefetch chunk 0 into registers
    short8 kreg[4], vreg[4];
#pragma unroll
    for (int s = 0; s < 4; ++s) {
        int seg = s * 256 + t;
        kreg[s] = *(const short8*)(Kg + ((seg >> 3)) * 64 + (seg & 7) * 8);
        vreg[s] = *(const short8*)(Vg + (seg >> 4) * 1024 + (seg & 15) * 8);
    }

    for (int jc = 0; jc < 8; ++jc) {
        if (jc) __syncthreads();   // previous chunk's LDS reads done
#pragma unroll
        for (int s = 0; s < 4; ++s) {
            int seg = s * 256 + t;
            *(short8*)(Ks + (seg >> 3) * KSTR + (seg & 7) * 8) = kreg[s];
            *(short8*)(Vs + (seg >> 4) * VSTR + (seg & 15) * 8) = vreg[s];
        }
        __syncthreads();
        if (jc < 7) {   // prefetch next chunk (latency hidden behind compute)
#pragma unroll
            for (int s = 0; s < 4; ++s) {
                int seg = s * 256 + t;
                kreg[s] = *(const short8*)(Kg + ((jc + 1) * 128 + (seg >> 3)) * 64 + (seg & 7) * 8);
                vreg[s] = *(const short8*)(Vg + (seg >> 4) * 1024 + (jc + 1) * 128 + (seg & 15) * 8);
            }
        }
        // bias fragments: one coalesced shortx4 per lane per 16x16 tile
        shortx4 bfv[2][8];
#pragma unroll
        for (int it = 0; it < 2; ++it)
#pragma unroll
            for (int jt = 0; jt < 8; ++jt)
                bfv[it][jt] = *(const shortx4*)(biasT + ((tib[it] + jc * 8 + jt) << 8) + lane * 4);
        // QK^T
        floatx4 sc[2][8];
#pragma unroll
        for (int jt = 0; jt < 8; ++jt) {
            short8 kb0 = *(const short8*)(Ks + (jt * 16 + fr) * KSTR + quad * 8);
            short8 kb1 = *(const short8*)(Ks + (jt * 16 + fr) * KSTR + 32 + quad * 8);
#pragma unroll
            for (int it = 0; it < 2; ++it) {
                floatx4 a = {0.f, 0.f, 0.f, 0.f};
                a = __builtin_amdgcn_mfma_f32_16x16x32_bf16(qf[it][0], kb0, a, 0, 0, 0);
                a = __builtin_amdgcn_mfma_f32_16x16x32_bf16(qf[it][1], kb1, a, 0, 0, 0);
                sc[it][jt] = a;
            }
        }
        // max-free softmax: scores bounded (|s| < ~10), fp32 exp is safe unshifted.
        // per-lane partial sums deferred to a single end-of-kernel reduce.
#pragma unroll
        for (int it = 0; it < 2; ++it)
#pragma unroll
            for (int jt = 0; jt < 8; ++jt)
#pragma unroll
                for (int r = 0; r < 4; ++r) {
                    float e = __expf(sc[it][jt][r] + bf2f(bfv[it][jt][r]));
                    psum[it][r] += e;
                    myP[(it * 16 + quad * 4 + r) * PSTR + jt * 16 + fr] = f2bf(e);
                }
        // PV (same-wave LDS round trip, in-order pipe; Vs guarded by barriers)
#pragma unroll
        for (int ks = 0; ks < 4; ++ks) {
            short8 pa[2], vb[4];
#pragma unroll
            for (int it = 0; it < 2; ++it)
                pa[it] = *(const short8*)(myP + (it * 16 + fr) * PSTR + ks * 32 + quad * 8);
#pragma unroll
            for (int dt = 0; dt < 4; ++dt)
                vb[dt] = *(const short8*)(Vs + (dt * 16 + fr) * VSTR + ks * 32 + quad * 8);
#pragma unroll
            for (int it = 0; it < 2; ++it)
#pragma unroll
                for (int dt = 0; dt < 4; ++dt)
                    pv[it][dt] = __builtin_amdgcn_mfma_f32_16x16x32_bf16(pa[it], vb[dt], pv[it][dt], 0, 0, 0);
        }
    }
    // single cross-lane reduce of the row sums
#pragma unroll
    for (int it = 0; it < 2; ++it)
#pragma unroll
        for (int r = 0; r < 4; ++r) {
#pragma unroll
            for (int mask = 8; mask >= 1; mask >>= 1)
                psum[it][r] += __shfl_xor(psum[it][r], mask);
        }
    // epilogue: normalize and store ctx
#pragma unroll
    for (int it = 0; it < 2; ++it)
#pragma unroll
        for (int dt = 0; dt < 4; ++dt)
#pragma unroll
            for (int r = 0; r < 4; ++r) {
                int i = i0 + w * 32 + it * 16 + quad * 4 + r;
                ctx[((b << 10) + i) * DMODEL + h * 64 + dt * 16 + fr] = f2bf(pv[it][dt][r] / psum[it][r]);
            }
}

extern "C" void kernel_launch(void* const* d_in, const int* in_sizes, int n_in,
                              void* d_out, int out_size, void* d_ws, size_t ws_size,
                              hipStream_t stream) {
    const float* x   = (const float*)d_in[0];
    const float* pf  = (const float*)d_in[1];
    const int*   ids = (const int*)d_in[2];
    const float* ss  = (const float*)d_in[3];
    const float* Wq  = (const float*)d_in[4];
    const float* Wk  = (const float*)d_in[5];
    const float* Wv  = (const float*)d_in[6];
    const float* Wo  = (const float*)d_in[7];
    const float* bo  = (const float*)d_in[8];
    const float* im  = (const float*)d_in[10];
    const float* ssw = (const float*)d_in[11];
    const float* ps  = (const float*)d_in[12];
    const float* dd  = (const float*)d_in[13];
    float* out = (float*)d_out;

    // ws plan (40 MB), overlays strictly stream-ordered:
    //  [0,8M):   xb (until gemm_qkv) -> biasT (bias_kernel..attn) -> Wob (cvt after attn)
    //  [8,16M):  Q   [16,24M): K   [24,32M): Vt
    //  [32,38M): Wb (until gemm_qkv) -> ctx [32,40M) (attn..gemm_out)
    //  [38,38.25M): proj (until bias_kernel)
    char* ws = (char*)d_ws;
    short* xb    = (short*)(ws);
    short* biasT = (short*)(ws);
    short* Wob   = (short*)(ws);
    short* Q     = (short*)(ws + (8u  << 20));
    short* K     = (short*)(ws + (16u << 20));
    short* Vt    = (short*)(ws + (24u << 20));
    short* Wb    = (short*)(ws + (32u << 20));
    short* ctx   = (short*)(ws + (32u << 20));
    float* proj  = (float*)(ws + (38u << 20));

    hipLaunchKernelGGL(cvt_kernel, dim3(2048), dim3(256), 0, stream, x, xb);
    hipLaunchKernelGGL(cvt_kernel, dim3(512), dim3(256), 0, stream, Wq, Wb);
    hipLaunchKernelGGL(cvt_kernel, dim3(512), dim3(256), 0, stream, Wk, Wb + (1u << 20));
    hipLaunchKernelGGL(cvt_kernel, dim3(512), dim3(256), 0, stream, Wv, Wb + (2u << 20));
    hipLaunchKernelGGL(proj_kernel, dim3(256), dim3(256), 0, stream, ss, ssw, proj);
    hipLaunchKernelGGL(gemm_qkv, dim3(32, 24), dim3(256), 0, stream, xb, Wb, Q, K, Vt);
    hipLaunchKernelGGL(bias_kernel, dim3(1024, 4), dim3(256), 0, stream,
                       pf, ids, im, proj, ps, dd, biasT);
    hipLaunchKernelGGL(attn_kernel, dim3(64, 8), dim3(256), 0, stream,
                       Q, K, Vt, biasT, ctx);
    hipLaunchKernelGGL(cvt_kernel, dim3(512), dim3(256), 0, stream, Wo, Wob);
    hipLaunchKernelGGL(gemm_out, dim3(32, 8), dim3(256), 0, stream, ctx, Wob, bo, out);
}

// Round 9
// 236.482 us; speedup vs baseline: 5.1664x; 1.0988x over previous
//
#include <hip/hip_runtime.h>

#define L_SEQ 1024
#define DMODEL 1024

typedef __attribute__((ext_vector_type(8))) short short8;
typedef __attribute__((ext_vector_type(4))) short shortx4;
typedef __attribute__((ext_vector_type(4))) float floatx4;

__device__ inline float bf2f(short s) {
    union { unsigned int u; float f; } v;
    v.u = ((unsigned int)(unsigned short)s) << 16;
    return v.f;
}
__device__ inline short f2bf(float f) {
    union { float f; unsigned int u; } v; v.f = f;
    unsigned int r = v.u + 0x7fff + ((v.u >> 16) & 1);
    return (short)(r >> 16);
}
__device__ inline void gload_lds16(const short* g, short* l) {
    __builtin_amdgcn_global_load_lds(
        (const __attribute__((address_space(1))) void*)g,
        (__attribute__((address_space(3))) void*)l, 16, 0, 0);
}

// ---------------- fp32 -> bf16 bulk convert (8 elems/thread) ----------------
__global__ __launch_bounds__(256) void cvt_kernel(const float* __restrict__ src,
                                                  short* __restrict__ dst) {
    int idx = blockIdx.x * 256 + threadIdx.x;
    const float4* p = (const float4*)src + idx * 2;
    float4 a = p[0], b = p[1];
    short8 r;
    r[0] = f2bf(a.x); r[1] = f2bf(a.y); r[2] = f2bf(a.z); r[3] = f2bf(a.w);
    r[4] = f2bf(b.x); r[5] = f2bf(b.y); r[6] = f2bf(b.z); r[7] = f2bf(b.w);
    *(short8*)(dst + idx * 8) = r;
}

// ---------------- proj = secondary_structure @ ss_w^T : (B*L, 16) fp32 ----------------
__global__ __launch_bounds__(256) void proj_kernel(const float* __restrict__ ss,
                                                   const float* __restrict__ ssw,
                                                   float* __restrict__ proj) {
    int idx = blockIdx.x * 256 + threadIdx.x;   // B*L*16 = 65536
    int h = idx & 15;
    int bl = idx >> 4;
    float s = 0.f;
#pragma unroll
    for (int d = 0; d < 8; ++d)
        s += ss[bl * 8 + d] * ssw[h * 8 + d];
    proj[bl * 16 + h] = s;
}

// ---------------- bias in MFMA-C tile order: [b][ti][tj][(iq*16+jf)*4 + ir] ----------------
// One thread computes the 4 ir-values of 4 consecutive j -> 4 contiguous shortx4
// (32 B/lane, full-line coalesced writes; kills the 4x partial-line amplification).
__global__ __launch_bounds__(256) void bias_kernel(const float* __restrict__ pf,
                                                   const int* __restrict__ ids,
                                                   const float* __restrict__ im,
                                                   const float* __restrict__ proj,
                                                   const float* __restrict__ ps,
                                                   const float* __restrict__ dd,
                                                   short* __restrict__ biasT) {
    int ti = blockIdx.x;            // i-tile (16 rows)
    int jc = blockIdx.y;            // j-chunk (256 cols)
    int b  = blockIdx.z;
    int t = threadIdx.x;
    int iq = t >> 6, lane = t & 63;
    float decay = fminf(fmaxf(dd[0], 0.1f), 5.0f);
    float psig = 1.f / (1.f + __expf(-ps[0]));

    __shared__ float pi[16][16];        // [i_local][h]
    __shared__ float interrow[16][25];  // [i_local][c]
    {
        int row = t >> 4, col = t & 15;
        pi[row][col] = proj[(((b << 10) + ti * 16 + row) << 4) + col];
        for (int e = t; e < 16 * 25; e += 256) {
            int il = e / 25, c = e - il * 25;
            int id_i = min(max(ids[(b << 10) + ti * 16 + il], 0), 24);
            interrow[il][c] = 0.5f * (im[id_i * 25 + c] + im[c * 25 + id_i]);
        }
    }
    __syncthreads();

    int j0 = jc * 256 + lane * 4;
    // pf for the 4 i-rows of this thread (i = ti*16 + iq*4 + ir), 16B coalesced each
    float4 pfv[4];
#pragma unroll
    for (int ir = 0; ir < 4; ++ir) {
        int i = ti * 16 + iq * 4 + ir;
        pfv[ir] = *(const float4*)(pf + (b << 20) + (i << 10) + j0);
    }
    int4 idj4 = *(const int4*)(ids + (b << 10) + j0);
    int idj[4] = {min(max(idj4.x, 0), 24), min(max(idj4.y, 0), 24),
                  min(max(idj4.z, 0), 24), min(max(idj4.w, 0), 24)};

    int tj = j0 >> 4, jf0 = j0 & 15;   // j0%4==0 so all 4 j share tj
    short* outp = biasT + ((((b << 6) + ti) << 6) + tj) * 256 + (iq * 16 + jf0) * 4;
#pragma unroll
    for (int e = 0; e < 4; ++e) {
        int j = j0 + e;
        const float4* pj4 = (const float4*)(proj + (((b << 10) + j) << 4));
        float4 p0 = pj4[0], p1 = pj4[1], p2 = pj4[2], p3 = pj4[3];
        float pfe = (e == 0) ? 0.f : 0.f;  // placeholder, resolved per ir below
        shortx4 o;
#pragma unroll
        for (int ir = 0; ir < 4; ++ir) {
            int i = ti * 16 + iq * 4 + ir;
            float dvr = (e == 0) ? pfv[ir].x : (e == 1) ? pfv[ir].y : (e == 2) ? pfv[ir].z : pfv[ir].w;
            float dist = fminf(fmaxf(dvr, 0.1f), 50.0f);
            float dp = -__expf(decay * __logf(dist)) * psig;
            int il = iq * 4 + ir;
            float inter = interrow[il][idj[e]] / (1.0f + fabsf((float)(i - j)));
            const float* pir = pi[il];
            float dot = pir[0] * p0.x + pir[1] * p0.y + pir[2] * p0.z + pir[3] * p0.w
                      + pir[4] * p1.x + pir[5] * p1.y + pir[6] * p1.z + pir[7] * p1.w
                      + pir[8] * p2.x + pir[9] * p2.y + pir[10] * p2.z + pir[11] * p2.w
                      + pir[12] * p3.x + pir[13] * p3.y + pir[14] * p3.z + pir[15] * p3.w;
            float st = 1.f / (1.f + __expf(-dot)) - 0.5f;
            o[ir] = f2bf(dp + inter + st);
        }
        *(shortx4*)(outp + e * 4) = o;
        (void)pfe;
    }
}

// ---------------- m97-style 128x128 GEMM: C = A(4096x1024) . B(3072x1024)^T ----------------
__global__ __launch_bounds__(256) void gemm_qkv(const short* __restrict__ xb,
                                                const short* __restrict__ Wb,
                                                short* __restrict__ Q,
                                                short* __restrict__ K,
                                                short* __restrict__ Vt) {
    __shared__ __align__(16) short As[128 * 32];
    __shared__ __align__(16) short Bs[128 * 32];
    int t = threadIdx.x;
    int wave = t >> 6, lane = t & 63, fr = lane & 15, quad = lane >> 4;
    int wm = (wave & 1) * 64, wn = (wave >> 1) * 64;
    int m0 = blockIdx.x * 128, n0 = blockIdx.y * 128;
    const short* Ag = xb + (m0 + (t >> 2)) * DMODEL + (t & 3) * 8;
    const short* Bg = Wb + (n0 + (t >> 2)) * DMODEL + (t & 3) * 8;
    short* Asd = As + t * 8;
    short* Bsd = Bs + t * 8;
    floatx4 acc[4][4] = {};
    for (int k0 = 0; k0 < DMODEL; k0 += 32) {
        __syncthreads();
        gload_lds16(Ag + k0, Asd);
        gload_lds16(Ag + 64 * DMODEL + k0, Asd + 2048);
        gload_lds16(Bg + k0, Bsd);
        gload_lds16(Bg + 64 * DMODEL + k0, Bsd + 2048);
        __syncthreads();
        short8 a[4], b[4];
#pragma unroll
        for (int i = 0; i < 4; ++i) {
            a[i] = *(const short8*)(As + (wm + i * 16 + fr) * 32 + quad * 8);
            b[i] = *(const short8*)(Bs + (wn + i * 16 + fr) * 32 + quad * 8);
        }
#pragma unroll
        for (int i = 0; i < 4; ++i)
#pragma unroll
            for (int j = 0; j < 4; ++j)
                acc[i][j] = __builtin_amdgcn_mfma_f32_16x16x32_bf16(a[i], b[j], acc[i][j], 0, 0, 0);
    }
#pragma unroll
    for (int i = 0; i < 4; ++i)
#pragma unroll
        for (int j = 0; j < 4; ++j)
#pragma unroll
            for (int r = 0; r < 4; ++r) {
                int m = m0 + wm + i * 16 + quad * 4 + r;
                int n = n0 + wn + j * 16 + fr;
                int b_ = m >> 10, ii = m & 1023;
                int mode = n >> 10, nn = n & 1023;
                int h = nn >> 6, d = nn & 63;
                float v = acc[i][j][r];
                if (mode == 0)
                    Q[((b_ * 16 + h) * L_SEQ + ii) * 64 + d] = f2bf(v * 0.125f);
                else if (mode == 1)
                    K[((b_ * 16 + h) * L_SEQ + ii) * 64 + d] = f2bf(v);
                else
                    Vt[((b_ * 16 + h) * 64 + d) * L_SEQ + ii] = f2bf(v);
            }
}

// ---------------- m97-style 128x128 GEMM: out = ctx(4096x1024) . Wo(1024x1024)^T + bo ----------------
__global__ __launch_bounds__(256) void gemm_out(const short* __restrict__ ctx,
                                                const short* __restrict__ Wob,
                                                const float* __restrict__ bo,
                                                float* __restrict__ out) {
    __shared__ __align__(16) short As[128 * 32];
    __shared__ __align__(16) short Bs[128 * 32];
    int t = threadIdx.x;
    int wave = t >> 6, lane = t & 63, fr = lane & 15, quad = lane >> 4;
    int wm = (wave & 1) * 64, wn = (wave >> 1) * 64;
    int m0 = blockIdx.x * 128, n0 = blockIdx.y * 128;
    const short* Ag = ctx + (m0 + (t >> 2)) * DMODEL + (t & 3) * 8;
    const short* Bg = Wob + (n0 + (t >> 2)) * DMODEL + (t & 3) * 8;
    short* Asd = As + t * 8;
    short* Bsd = Bs + t * 8;
    floatx4 acc[4][4] = {};
    for (int k0 = 0; k0 < DMODEL; k0 += 32) {
        __syncthreads();
        gload_lds16(Ag + k0, Asd);
        gload_lds16(Ag + 64 * DMODEL + k0, Asd + 2048);
        gload_lds16(Bg + k0, Bsd);
        gload_lds16(Bg + 64 * DMODEL + k0, Bsd + 2048);
        __syncthreads();
        short8 a[4], b[4];
#pragma unroll
        for (int i = 0; i < 4; ++i) {
            a[i] = *(const short8*)(As + (wm + i * 16 + fr) * 32 + quad * 8);
            b[i] = *(const short8*)(Bs + (wn + i * 16 + fr) * 32 + quad * 8);
        }
#pragma unroll
        for (int i = 0; i < 4; ++i)
#pragma unroll
            for (int j = 0; j < 4; ++j)
                acc[i][j] = __builtin_amdgcn_mfma_f32_16x16x32_bf16(a[i], b[j], acc[i][j], 0, 0, 0);
    }
#pragma unroll
    for (int i = 0; i < 4; ++i)
#pragma unroll
        for (int j = 0; j < 4; ++j)
#pragma unroll
            for (int r = 0; r < 4; ++r) {
                int m = m0 + wm + i * 16 + quad * 4 + r;
                int n = n0 + wn + j * 16 + fr;
                out[m * DMODEL + n] = acc[i][j][r] + bo[n];
            }
}

// ---------------- flash attention, max-free softmax, double-buffered K/V ----------------
#define KSTR 72
#define VSTR 136
#define PSTR 136
__global__ __launch_bounds__(256, 2) void attn_kernel(const short* __restrict__ Q,
                                                      const short* __restrict__ K,
                                                      const short* __restrict__ Vt,
                                                      const short* __restrict__ biasT,
                                                      short* __restrict__ ctx) {
    __shared__ __align__(16) short Ks[128 * KSTR];          // 18432 B
    __shared__ __align__(16) short Vs[64 * VSTR];           // 17408 B
    __shared__ __align__(16) short Ps[4 * 2 * 16 * PSTR];   // 34816 B
    int bh = blockIdx.x;            // b*16+h
    int b = bh >> 4, h = bh & 15;
    int i0 = blockIdx.y * 128;
    int t = threadIdx.x;
    int w = t >> 6, lane = t & 63, fr = lane & 15, quad = lane >> 4;
    const short* Kg = K + (bh << 16);
    const short* Vg = Vt + (bh << 16);
    short* myP = Ps + w * (2 * 16 * PSTR);
    // bias tile-row bases (×64) for this wave's two i-tiles
    int tib[2];
    tib[0] = (((b << 6) + (i0 >> 4) + w * 2) << 6);
    tib[1] = tib[0] + 64;

    // Q fragments for this wave's 32 rows (2 tiles of 16)
    short8 qf[2][2];
#pragma unroll
    for (int it = 0; it < 2; ++it) {
        const short8* qp = (const short8*)(Q + ((bh << 10) + i0 + w * 32 + it * 16 + fr) * 64 + quad * 8);
        qf[it][0] = qp[0];
        qf[it][1] = qp[4];
    }
    float psum[2][4] = {};
    floatx4 pv[2][4] = {};

    // prefetch chunk 0 into registers
    short8 kreg[4], vreg[4];
#pragma unroll
    for (int s = 0; s < 4; ++s) {
        int seg = s * 256 + t;
        kreg[s] = *(const short8*)(Kg + ((seg >> 3)) * 64 + (seg & 7) * 8);
        vreg[s] = *(const short8*)(Vg + (seg >> 4) * 1024 + (seg & 15) * 8);
    }

    for (int jc = 0; jc < 8; ++jc) {
        if (jc) __syncthreads();   // previous chunk's LDS reads done
#pragma unroll
        for (int s = 0; s < 4; ++s) {
            int seg = s * 256 + t;
            *(short8*)(Ks + (seg >> 3) * KSTR + (seg & 7) * 8) = kreg[s];
            *(short8*)(Vs + (seg >> 4) * VSTR + (seg & 15) * 8) = vreg[s];
        }
        __syncthreads();
        if (jc < 7) {   // prefetch next chunk (latency hidden behind compute)
#pragma unroll
            for (int s = 0; s < 4; ++s) {
                int seg = s * 256 + t;
                kreg[s] = *(const short8*)(Kg + ((jc + 1) * 128 + (seg >> 3)) * 64 + (seg & 7) * 8);
                vreg[s] = *(const short8*)(Vg + (seg >> 4) * 1024 + (jc + 1) * 128 + (seg & 15) * 8);
            }
        }
        // bias fragments: one coalesced shortx4 per lane per 16x16 tile
        shortx4 bfv[2][8];
#pragma unroll
        for (int it = 0; it < 2; ++it)
#pragma unroll
            for (int jt = 0; jt < 8; ++jt)
                bfv[it][jt] = *(const shortx4*)(biasT + ((tib[it] + jc * 8 + jt) << 8) + lane * 4);
        // QK^T
        floatx4 sc[2][8];
#pragma unroll
        for (int jt = 0; jt < 8; ++jt) {
            short8 kb0 = *(const short8*)(Ks + (jt * 16 + fr) * KSTR + quad * 8);
            short8 kb1 = *(const short8*)(Ks + (jt * 16 + fr) * KSTR + 32 + quad * 8);
#pragma unroll
            for (int it = 0; it < 2; ++it) {
                floatx4 a = {0.f, 0.f, 0.f, 0.f};
                a = __builtin_amdgcn_mfma_f32_16x16x32_bf16(qf[it][0], kb0, a, 0, 0, 0);
                a = __builtin_amdgcn_mfma_f32_16x16x32_bf16(qf[it][1], kb1, a, 0, 0, 0);
                sc[it][jt] = a;
            }
        }
        // max-free softmax: scores bounded (|s| < ~10), fp32 exp is safe unshifted.
#pragma unroll
        for (int it = 0; it < 2; ++it)
#pragma unroll
            for (int jt = 0; jt < 8; ++jt)
#pragma unroll
                for (int r = 0; r < 4; ++r) {
                    float e = __expf(sc[it][jt][r] + bf2f(bfv[it][jt][r]));
                    psum[it][r] += e;
                    myP[(it * 16 + quad * 4 + r) * PSTR + jt * 16 + fr] = f2bf(e);
                }
        // PV (same-wave LDS round trip, in-order pipe; Vs guarded by barriers)
#pragma unroll
        for (int ks = 0; ks < 4; ++ks) {
            short8 pa[2], vb[4];
#pragma unroll
            for (int it = 0; it < 2; ++it)
                pa[it] = *(const short8*)(myP + (it * 16 + fr) * PSTR + ks * 32 + quad * 8);
#pragma unroll
            for (int dt = 0; dt < 4; ++dt)
                vb[dt] = *(const short8*)(Vs + (dt * 16 + fr) * VSTR + ks * 32 + quad * 8);
#pragma unroll
            for (int it = 0; it < 2; ++it)
#pragma unroll
                for (int dt = 0; dt < 4; ++dt)
                    pv[it][dt] = __builtin_amdgcn_mfma_f32_16x16x32_bf16(pa[it], vb[dt], pv[it][dt], 0, 0, 0);
        }
    }
    // single cross-lane reduce of the row sums
#pragma unroll
    for (int it = 0; it < 2; ++it)
#pragma unroll
        for (int r = 0; r < 4; ++r) {
#pragma unroll
            for (int mask = 8; mask >= 1; mask >>= 1)
                psum[it][r] += __shfl_xor(psum[it][r], mask);
        }
    // epilogue: normalize and store ctx
#pragma unroll
    for (int it = 0; it < 2; ++it)
#pragma unroll
        for (int dt = 0; dt < 4; ++dt)
#pragma unroll
            for (int r = 0; r < 4; ++r) {
                int i = i0 + w * 32 + it * 16 + quad * 4 + r;
                ctx[((b << 10) + i) * DMODEL + h * 64 + dt * 16 + fr] = f2bf(pv[it][dt][r] / psum[it][r]);
            }
}

extern "C" void kernel_launch(void* const* d_in, const int* in_sizes, int n_in,
                              void* d_out, int out_size, void* d_ws, size_t ws_size,
                              hipStream_t stream) {
    const float* x   = (const float*)d_in[0];
    const float* pf  = (const float*)d_in[1];
    const int*   ids = (const int*)d_in[2];
    const float* ss  = (const float*)d_in[3];
    const float* Wq  = (const float*)d_in[4];
    const float* Wk  = (const float*)d_in[5];
    const float* Wv  = (const float*)d_in[6];
    const float* Wo  = (const float*)d_in[7];
    const float* bo  = (const float*)d_in[8];
    const float* im  = (const float*)d_in[10];
    const float* ssw = (const float*)d_in[11];
    const float* ps  = (const float*)d_in[12];
    const float* dd  = (const float*)d_in[13];
    float* out = (float*)d_out;

    // ws plan (40 MB), overlays strictly stream-ordered:
    //  [0,8M):   xb (until gemm_qkv) -> biasT (bias_kernel..attn) -> Wob (cvt after attn)
    //  [8,16M):  Q   [16,24M): K   [24,32M): Vt
    //  [32,38M): Wb (until gemm_qkv) -> ctx [32,40M) (attn..gemm_out)
    //  [38,38.25M): proj (until bias_kernel)
    char* ws = (char*)d_ws;
    short* xb    = (short*)(ws);
    short* biasT = (short*)(ws);
    short* Wob   = (short*)(ws);
    short* Q     = (short*)(ws + (8u  << 20));
    short* K     = (short*)(ws + (16u << 20));
    short* Vt    = (short*)(ws + (24u << 20));
    short* Wb    = (short*)(ws + (32u << 20));
    short* ctx   = (short*)(ws + (32u << 20));
    float* proj  = (float*)(ws + (38u << 20));

    hipLaunchKernelGGL(cvt_kernel, dim3(2048), dim3(256), 0, stream, x, xb);
    hipLaunchKernelGGL(cvt_kernel, dim3(512), dim3(256), 0, stream, Wq, Wb);
    hipLaunchKernelGGL(cvt_kernel, dim3(512), dim3(256), 0, stream, Wk, Wb + (1u << 20));
    hipLaunchKernelGGL(cvt_kernel, dim3(512), dim3(256), 0, stream, Wv, Wb + (2u << 20));
    hipLaunchKernelGGL(proj_kernel, dim3(256), dim3(256), 0, stream, ss, ssw, proj);
    hipLaunchKernelGGL(gemm_qkv, dim3(32, 24), dim3(256), 0, stream, xb, Wb, Q, K, Vt);
    hipLaunchKernelGGL(bias_kernel, dim3(64, 4, 4), dim3(256), 0, stream,
                       pf, ids, im, proj, ps, dd, biasT);
    hipLaunchKernelGGL(attn_kernel, dim3(64, 8), dim3(256), 0, stream,
                       Q, K, Vt, biasT, ctx);
    hipLaunchKernelGGL(cvt_kernel, dim3(512), dim3(256), 0, stream, Wo, Wob);
    hipLaunchKernelGGL(gemm_out, dim3(32, 8), dim3(256), 0, stream, ctx, Wob, bo, out);
}